// Round 2
// baseline (2495.519 us; speedup 1.0000x reference)
//
#include <hip/hip_runtime.h>
#include <hip/hip_bf16.h>
#include <stdint.h>

typedef __hip_bfloat16 bf16;

#define N_   4096
#define NP   32768   // B*N
#define KNN  20

// ---- workspace layout (units: float) ----
#define OFF_H2   0L         // 32768*64 ; later reused as hsn output
#define OFF_XYZ  2097152L   // 32768*3
#define OFF_XX   2195456L   // 32768  (|h2|^2)
#define OFF_XXC  2228224L   // 32768  (|x|^2)
#define OFF_IDX1 2260992L   // 32768*20 int
#define OFF_IDX2 2916352L   // 32768*20 int
#define OFF_WF   3571712L   // 104768 fp32 weights
#define OFF_FLAG 3676480L   // dtype flag (int), 64-float slot
#define OFF_PAIR 3676544L   // pair chunk lives here during kNN phase
// post-kNN reuse of the pair region:
#define OFF_U    3676544L   // 32768*64 ; u=(Wa-Wb)h2 ; later w = Wsn1*hdg
#define OFF_V    5773696L   // 32768*64 ; v = Wb*h2
#define OFF_HDG  7870848L   // 32768*64
// minimum ws: (7870848+2097152)*4 = 39.9 MB ; full pair adds up to 64 MB

// ---- fp32 weight bank offsets ----
#define WF_W1 0
#define WF_G1 192
#define WF_B1 256
#define WF_W2 320
#define WF_G2 4416
#define WF_B2 4480
#define WF_WDG1 4544
#define WF_GDG1 12736
#define WF_BDG1 12800
#define WF_WDG2 12864
#define WF_GDG2 16960
#define WF_BDG2 17024
#define WF_WSN1 17088
#define WF_GSN1 21184
#define WF_BSN1 21248
#define WF_WSN2 21312
#define WF_GSN2 25408
#define WF_BSN2 25472
#define WF_W3 25536
#define WF_G3 29632
#define WF_B3 29696
#define WF_W4 29760
#define WF_G4 37952
#define WF_B4 38080
#define WF_W5 38208
#define WF_G5 103744
#define WF_B5 104256
#define WF_END 104768

__device__ __forceinline__ float lrelu(float x){ return x >= 0.f ? x : 0.01f*x; }

// ---------------- K-1: dtype detect (1 = fp32 inputs, 0 = bf16) -------------
// Read x as bf16 pairs; even-index elements are genuine values iff data is bf16.
__global__ void k_detect(const void* __restrict__ x, int* __restrict__ flag){
  int lane = threadIdx.x;
  const bf16* xb = (const bf16*)x;
  int cnt = 0;
  #pragma unroll 1
  for (int i = lane; i < 256; i += 64){
    float v = __bfloat162float(xb[2*i]);      // even elements
    float a = fabsf(v);
    if (a > 1e-3f && a < 100.f) cnt++;
  }
  #pragma unroll
  for (int off = 32; off; off >>= 1) cnt += __shfl_down(cnt, off, 64);
  if (lane == 0) *flag = (cnt >= 128) ? 0 : 1;   // many sane evens -> bf16
}

// ---------------- K0: convert all weights -> fp32 bank ----------------------
struct WPack {
  const void* p[27];
  int off[28];
};

__global__ void k_wcvt(WPack pk, float* __restrict__ dst, const int* __restrict__ flagp){
  int i = blockIdx.x*256 + threadIdx.x;
  if (i >= WF_END) return;
  int f = *flagp;
  #pragma unroll 1
  for (int s = 0; s < 27; s++){
    if (i < pk.off[s+1]){
      int j = i - pk.off[s];
      dst[i] = f ? ((const float*)pk.p[s])[j]
                 : __bfloat162float(((const bf16*)pk.p[s])[j]);
      return;
    }
  }
}

// ---------------- K1: per-point MLP1+MLP2, norms, coords --------------------
__global__ void k_point(const void* __restrict__ x, float* __restrict__ ws){
  const float* wf = ws + OFF_WF;
  int f = ((const int*)(ws + OFF_FLAG))[0];
  int n = blockIdx.x*256 + threadIdx.x;
  float x0, x1, x2;
  if (f){
    const float* xf = (const float*)x;
    x0 = xf[n*3+0]; x1 = xf[n*3+1]; x2 = xf[n*3+2];
  } else {
    const bf16* xb = (const bf16*)x;
    x0 = __bfloat162float(xb[n*3+0]);
    x1 = __bfloat162float(xb[n*3+1]);
    x2 = __bfloat162float(xb[n*3+2]);
  }

  float h1[64];
  #pragma unroll
  for (int o=0;o<64;o++){
    float a = wf[WF_W1+o*3+0]*x0 + wf[WF_W1+o*3+1]*x1 + wf[WF_W1+o*3+2]*x2;
    h1[o] = lrelu(wf[WF_G1+o]*a + wf[WF_B1+o]);
  }
  float xx = 0.f;
  #pragma unroll 1
  for (int o=0;o<64;o++){
    float a = 0.f;
    #pragma unroll
    for (int c=0;c<64;c++) a += wf[WF_W2+o*64+c]*h1[c];
    float h2 = lrelu(wf[WF_G2+o]*a + wf[WF_B2+o]);
    ws[OFF_H2 + (long)n*64 + o] = h2;
    xx += h2*h2;
  }
  ws[OFF_XX + n] = xx;
  ws[OFF_XYZ + n*3+0] = x0; ws[OFF_XYZ + n*3+1] = x1; ws[OFF_XYZ + n*3+2] = x2;
  ws[OFF_XXC + n] = x0*x0 + x1*x1 + x2*x2;
}

// ---------------- K2a: pair GEMM (fp32), per batch chunk --------------------
// pair[n][m] = 2*dot(h2_n,h2_m) - xx[m]   (row-constant -xx[n] dropped)
__global__ __launch_bounds__(256) void k_pair(const float* __restrict__ ws, float* __restrict__ pair,
                                              int b, int n0){
  __shared__ float As[64*128];
  __shared__ float Bs[64*128];
  int t = threadIdx.x;
  int bx = blockIdx.x, by = blockIdx.y;
  const float* h2 = ws + OFF_H2 + (long)b*N_*64;

  int r = t >> 1, c0 = (t & 1)*32;
  const float4* arow = (const float4*)(h2 + (long)(n0 + by*128 + r)*64 + c0);
  const float4* brow = (const float4*)(h2 + (long)(bx*128 + r)*64 + c0);
  #pragma unroll
  for (int q=0;q<8;q++){
    float4 av = arow[q];
    As[(c0+4*q+0)*128 + r] = av.x; As[(c0+4*q+1)*128 + r] = av.y;
    As[(c0+4*q+2)*128 + r] = av.z; As[(c0+4*q+3)*128 + r] = av.w;
    float4 bv = brow[q];
    Bs[(c0+4*q+0)*128 + r] = bv.x; Bs[(c0+4*q+1)*128 + r] = bv.y;
    Bs[(c0+4*q+2)*128 + r] = bv.z; Bs[(c0+4*q+3)*128 + r] = bv.w;
  }
  __syncthreads();

  int tr = t/16, tc = t%16;
  float acc[8][8] = {};
  #pragma unroll 4
  for (int k=0;k<64;k++){
    const float4* ap = (const float4*)&As[k*128 + tr*8];
    const float4* bp = (const float4*)&Bs[k*128 + tc*8];
    float4 a0 = ap[0], a1 = ap[1], c0v = bp[0], c1v = bp[1];
    float a[8] = {a0.x,a0.y,a0.z,a0.w,a1.x,a1.y,a1.z,a1.w};
    float c[8] = {c0v.x,c0v.y,c0v.z,c0v.w,c1v.x,c1v.y,c1v.z,c1v.w};
    #pragma unroll
    for (int i=0;i<8;i++)
      #pragma unroll
      for (int j=0;j<8;j++) acc[i][j] += a[i]*c[j];
  }
  const float* xxp = ws + OFF_XX + b*N_ + bx*128 + tc*8;
  float xxm[8];
  #pragma unroll
  for (int j=0;j<8;j++) xxm[j] = xxp[j];
  #pragma unroll
  for (int i=0;i<8;i++){
    long row = (long)(by*128 + tr*8 + i)*N_ + bx*128 + tc*8;
    float4 o0 = make_float4(2.f*acc[i][0]-xxm[0], 2.f*acc[i][1]-xxm[1],
                            2.f*acc[i][2]-xxm[2], 2.f*acc[i][3]-xxm[3]);
    float4 o1 = make_float4(2.f*acc[i][4]-xxm[4], 2.f*acc[i][5]-xxm[5],
                            2.f*acc[i][6]-xxm[6], 2.f*acc[i][7]-xxm[7]);
    ((float4*)(pair+row))[0] = o0;
    ((float4*)(pair+row))[1] = o1;
  }
}

// ---------------- exact top-20 of a 4096-row in LDS, one wave ---------------
__device__ __forceinline__ void wave_topk(float* row, int lane, int* __restrict__ out){
  float mv = -3.0e38f; int mi = 0;
  #pragma unroll 1
  for (int i=0;i<64;i++){
    int m = i*64 + lane;
    float v = row[m];
    if (v > mv){ mv = v; mi = m; }       // ascending scan -> min-index tiebreak
  }
  for (int tt=0; tt<KNN; tt++){
    float gv = mv; int gi = mi;
    #pragma unroll
    for (int off=1; off<64; off<<=1){
      float ov = __shfl_xor(gv, off, 64);
      int   oi = __shfl_xor(gi, off, 64);
      if (ov > gv || (ov == gv && oi < gi)){ gv = ov; gi = oi; }
    }
    if (lane == 0){ out[tt] = gi; row[gi] = -3.0e38f; }
    __syncthreads();
    int js = gi & 63;                     // winner's lane-class
    int m = lane*64 + js;
    float nv = row[m]; int ni = m;
    #pragma unroll
    for (int off=1; off<64; off<<=1){
      float ov = __shfl_xor(nv, off, 64);
      int   oi = __shfl_xor(ni, off, 64);
      if (ov > nv || (ov == nv && oi < ni)){ nv = ov; ni = oi; }
    }
    if (lane == js){ mv = nv; mi = ni; }
  }
}

// ---------------- K2b: top-20 over stored pair rows -------------------------
__global__ __launch_bounds__(64) void k_topk_pair(const float* __restrict__ pair, int* __restrict__ idx1,
                                                  int b, int n0){
  __shared__ float row[4096];
  int rl = blockIdx.x, lane = threadIdx.x;
  const float4* src = (const float4*)(pair + (long)rl*N_);
  #pragma unroll
  for (int i=0;i<16;i++) ((float4*)row)[lane + 64*i] = src[lane + 64*i];
  __syncthreads();
  wave_topk(row, lane, idx1 + (long)(b*N_ + n0 + rl)*KNN);
}

// ---------------- K3: fused coord-space kNN ---------------------------------
__global__ __launch_bounds__(64) void k_knn2(const float* __restrict__ ws, int* __restrict__ idx2){
  __shared__ float row[4096];
  int n = blockIdx.x, lane = threadIdx.x;
  int base = (n >> 12) << 12;
  const float* xyz = ws + OFF_XYZ;
  float xn = xyz[(long)n*3+0], yn = xyz[(long)n*3+1], zn = xyz[(long)n*3+2];
  #pragma unroll 1
  for (int i=0;i<64;i++){
    int m = i*64 + lane;
    const float* pm = xyz + (long)(base+m)*3;
    float d = xn*pm[0] + yn*pm[1] + zn*pm[2];
    row[m] = 2.f*d - ws[OFF_XXC + base + m];
  }
  __syncthreads();
  wave_topk(row, lane, idx2 + (long)n*KNN);
}

// ---------------- K3b: u = (Wa-Wb)h2, v = Wb h2 (post-kNN) ------------------
__global__ void k_uv(float* __restrict__ ws){
  const float* wf = ws + OFF_WF;
  int n = blockIdx.x*256 + threadIdx.x;
  float h[64];
  const float4* src = (const float4*)(ws + OFF_H2 + (long)n*64);
  #pragma unroll
  for (int q=0;q<16;q++){ float4 v = src[q]; h[4*q]=v.x; h[4*q+1]=v.y; h[4*q+2]=v.z; h[4*q+3]=v.w; }
  #pragma unroll 1
  for (int o=0;o<64;o++){
    float va=0.f, vb=0.f;
    #pragma unroll
    for (int c=0;c<64;c++){
      va += wf[WF_WDG1+o*128+c]*h[c];
      vb += wf[WF_WDG1+o*128+64+c]*h[c];
    }
    ws[OFF_U + (long)n*64 + o] = va - vb;
    ws[OFF_V + (long)n*64 + o] = vb;
  }
}

// ---------------- K4/K5: edge stage (gathered first conv folded) ------------
__global__ __launch_bounds__(256) void k_edge(float* __restrict__ ws, const int* __restrict__ idxt,
      int use_u, long uoff, long goff, int w2off,
      int g1off, int b1off, int g2off, int b2off, long outoff){
  __shared__ float y1s[64*65];
  __shared__ float w2s[64*65];
  __shared__ float us [64*65];
  __shared__ float g1s[64], b1s[64], g2s[64], b2s[64];
  const float* wf = ws + OFF_WF;
  int t = threadIdx.x;
  int p0 = blockIdx.x*64;
  int b  = p0 >> 12;

  #pragma unroll 1
  for (int i=t;i<4096;i+=256){ int o = i>>6, kk = i&63; w2s[o*65+kk] = wf[w2off + i]; }
  if (use_u){
    #pragma unroll 1
    for (int i=t;i<4096;i+=256){ int e = i>>6, c = i&63; us[e*65+c] = ws[uoff + (long)(p0+e)*64 + c]; }
  }
  if (t < 64){ g1s[t]=wf[g1off+t]; b1s[t]=wf[b1off+t]; g2s[t]=wf[g2off+t]; b2s[t]=wf[b2off+t]; }
  __syncthreads();

  int lane = t & 63, wv = t >> 6;
  int tr = t & 15, oc = t >> 4;
  float mx[4][4];
  #pragma unroll
  for (int i=0;i<4;i++)
    #pragma unroll
    for (int j=0;j<4;j++) mx[i][j] = -3.0e38f;

  for (int k=0;k<KNN;k++){
    #pragma unroll 4
    for (int jj=0;jj<16;jj++){
      int e  = wv + 4*jj;
      int nb = idxt[(long)(p0+e)*KNN + k];
      float val = ws[goff + ((long)(b<<12) + nb)*64 + lane];
      if (use_u) val += us[e*65 + lane];
      y1s[e*65 + lane] = lrelu(g1s[lane]*val + b1s[lane]);
    }
    __syncthreads();
    float acc[4][4] = {};
    #pragma unroll 4
    for (int kk=0;kk<64;kk++){
      float a0 = y1s[(tr   )*65+kk], a1 = y1s[(tr+16)*65+kk];
      float a2 = y1s[(tr+32)*65+kk], a3 = y1s[(tr+48)*65+kk];
      float c0 = w2s[(oc   )*65+kk], c1 = w2s[(oc+16)*65+kk];
      float c2 = w2s[(oc+32)*65+kk], c3 = w2s[(oc+48)*65+kk];
      acc[0][0]+=a0*c0; acc[0][1]+=a0*c1; acc[0][2]+=a0*c2; acc[0][3]+=a0*c3;
      acc[1][0]+=a1*c0; acc[1][1]+=a1*c1; acc[1][2]+=a1*c2; acc[1][3]+=a1*c3;
      acc[2][0]+=a2*c0; acc[2][1]+=a2*c1; acc[2][2]+=a2*c2; acc[2][3]+=a2*c3;
      acc[3][0]+=a3*c0; acc[3][1]+=a3*c1; acc[3][2]+=a3*c2; acc[3][3]+=a3*c3;
    }
    #pragma unroll
    for (int i=0;i<4;i++)
      #pragma unroll
      for (int j=0;j<4;j++){
        int o = oc + 16*j;
        float yy = lrelu(g2s[o]*acc[i][j] + b2s[o]);
        mx[i][j] = fmaxf(mx[i][j], yy);
      }
    __syncthreads();
  }
  #pragma unroll
  for (int i=0;i<4;i++)
    #pragma unroll
    for (int j=0;j<4;j++)
      ws[outoff + (long)(p0 + tr + 16*i)*64 + oc + 16*j] = mx[i][j];
}

// ---------------- K4b: w = Wsn1 . hdg per point (stored raw) ----------------
__global__ void k_w(float* __restrict__ ws){
  const float* wf = ws + OFF_WF;
  int n = blockIdx.x*256 + threadIdx.x;
  float h[64];
  const float4* src = (const float4*)(ws + OFF_HDG + (long)n*64);
  #pragma unroll
  for (int q=0;q<16;q++){ float4 v = src[q]; h[4*q]=v.x; h[4*q+1]=v.y; h[4*q+2]=v.z; h[4*q+3]=v.w; }
  #pragma unroll 1
  for (int o=0;o<64;o++){
    float a = 0.f;
    #pragma unroll
    for (int c=0;c<64;c++) a += wf[WF_WSN1 + o*64 + c]*h[c];
    ws[OFF_U + (long)n*64 + o] = a;   // u buffer reused for w
  }
}

// ---------------- K6: head conv3->conv4->conv5 ------------------------------
__global__ void k_final(const float* __restrict__ ws, void* __restrict__ outv){
  const float* wf = ws + OFF_WF;
  int f = ((const int*)(ws + OFF_FLAG))[0];
  int n = blockIdx.x*256 + threadIdx.x;
  int g = blockIdx.y;
  int b = n >> 12, nn = n & 4095;
  float h[64];
  const float4* src = (const float4*)(ws + OFF_H2 + (long)n*64);   // hsn lives here
  #pragma unroll
  for (int q=0;q<16;q++){ float4 v = src[q]; h[4*q]=v.x; h[4*q+1]=v.y; h[4*q+2]=v.z; h[4*q+3]=v.w; }
  float h3[64];
  #pragma unroll 1
  for (int o=0;o<64;o++){
    float a = 0.f;
    #pragma unroll
    for (int c=0;c<64;c++) a += wf[WF_W3+o*64+c]*h[c];
    h3[o] = lrelu(wf[WF_G3+o]*a + wf[WF_B3+o]);
  }
  float h4[128];
  #pragma unroll 1
  for (int o=0;o<128;o++){
    float a = 0.f;
    #pragma unroll
    for (int c=0;c<64;c++) a += wf[WF_W4+o*64+c]*h3[c];
    h4[o] = lrelu(wf[WF_G4+o]*a + wf[WF_B4+o]);
  }
  #pragma unroll 1
  for (int o=0;o<128;o++){
    int oo = g*128 + o;
    float a = 0.f;
    #pragma unroll
    for (int c=0;c<128;c++) a += wf[WF_W5 + oo*128 + c]*h4[c];
    a = lrelu(wf[WF_G5+oo]*a + wf[WF_B5+oo]);
    long oi = ((long)(b*512 + oo) << 12) + nn;
    if (f) ((float*)outv)[oi] = a;
    else   ((bf16*)outv)[oi] = __float2bfloat16(a);
  }
}

// ---------------- host ------------------------------------------------------
extern "C" void kernel_launch(void* const* d_in, const int* in_sizes, int n_in,
                              void* d_out, int out_size, void* d_ws, size_t ws_size,
                              hipStream_t stream) {
  const void* X = d_in[0];
  float* ws = (float*)d_ws;
  int* flagp = (int*)(ws + OFF_FLAG);

  WPack pk;
  static const int wsz[27] = {192,64,64, 4096,64,64, 8192,64,64, 4096,64,64, 4096,64,64,
                              4096,64,64, 4096,64,64, 8192,128,128, 65536,512,512};
  int off = 0;
  for (int i=0;i<27;i++){ pk.p[i] = d_in[i+1]; pk.off[i] = off; off += wsz[i]; }
  pk.off[27] = off;

  k_detect<<<dim3(1), dim3(64), 0, stream>>>(X, flagp);
  k_wcvt<<<dim3((WF_END+255)/256), dim3(256), 0, stream>>>(pk, ws + OFF_WF, flagp);
  k_point<<<dim3(NP/256), dim3(256), 0, stream>>>(X, ws);
  k_knn2<<<dim3(NP), dim3(64), 0, stream>>>(ws, (int*)(ws + OFF_IDX2));

  long availf = (long)(ws_size/4) - OFF_PAIR;
  int chunk = 4096;
  if (availf < (long)N_*N_){
    long c = (availf / N_) & ~127L;
    chunk = (int)(c < 128 ? 128 : c);
    if (chunk > 4096) chunk = 4096;
  }
  for (int b=0;b<8;b++){
    for (int n0=0;n0<N_; n0+=chunk){
      int rows = (N_ - n0 < chunk) ? (N_ - n0) : chunk;
      k_pair<<<dim3(32, rows/128), dim3(256), 0, stream>>>(ws, ws + OFF_PAIR, b, n0);
      k_topk_pair<<<dim3(rows), dim3(64), 0, stream>>>(ws + OFF_PAIR, (int*)(ws + OFF_IDX1), b, n0);
    }
  }
  // u,v AFTER kNN (pair region reused)
  k_uv<<<dim3(NP/256), dim3(256), 0, stream>>>(ws);
  // dg stage: y1 = lrelu(gdg1*(u + v[nbr1]) + bdg1); y2 = lrelu(gdg2*(Wdg2.y1)+bdg2); max_k -> hdg
  k_edge<<<dim3(NP/64), dim3(256), 0, stream>>>(ws, (const int*)(ws + OFF_IDX1),
        1, OFF_U, OFF_V, WF_WDG2, WF_GDG1, WF_BDG1, WF_GDG2, WF_BDG2, OFF_HDG);
  // w = Wsn1 . hdg (into OFF_U)
  k_w<<<dim3(NP/256), dim3(256), 0, stream>>>(ws);
  // sn stage: y1 = lrelu(gsn1*w[nbr2] + bsn1); y2 = lrelu(gsn2*(Wsn2.y1)+bsn2); max_k -> hsn
  k_edge<<<dim3(NP/64), dim3(256), 0, stream>>>(ws, (const int*)(ws + OFF_IDX2),
        0, 0, OFF_U, WF_WSN2, WF_GSN1, WF_BSN1, WF_GSN2, WF_BSN2, OFF_H2);
  k_final<<<dim3(NP/256, 4), dim3(256), 0, stream>>>(ws, d_out);
}

// Round 3
// 2185.561 us; speedup vs baseline: 1.1418x; 1.1418x over previous
//
#include <hip/hip_runtime.h>
#include <hip/hip_bf16.h>
#include <stdint.h>

typedef __hip_bfloat16 bf16;

#define N_   4096
#define NP   32768   // B*N
#define KNN  20

// ---- workspace layout (units: float) ----
#define OFF_H2   0L         // 32768*64 ; later reused as hsn output
#define OFF_XYZ  2097152L   // 3 planes of 32768 (SoA)
#define OFF_X    2097152L
#define OFF_Y    2129920L
#define OFF_Z    2162688L
#define OFF_XX   2195456L   // 32768  (|h2|^2)
#define OFF_XXC  2228224L   // 32768  (|x|^2)
#define OFF_IDX1 2260992L   // 32768*20 int
#define OFF_IDX2 2916352L   // 32768*20 int
#define OFF_WF   3571712L   // 104768 fp32 weights
#define OFF_FLAG 3676480L   // dtype flag (int), 64-float slot
#define OFF_PAIR 3676544L   // pair chunk lives here during kNN phase
// post-kNN reuse of the pair region:
#define OFF_U    3676544L   // 32768*64 ; u=(Wa-Wb)h2 ; later w = Wsn1*hdg
#define OFF_V    5773696L   // 32768*64 ; v = Wb*h2
#define OFF_HDG  7870848L   // 32768*64

// ---- fp32 weight bank offsets ----
#define WF_W1 0
#define WF_G1 192
#define WF_B1 256
#define WF_W2 320
#define WF_G2 4416
#define WF_B2 4480
#define WF_WDG1 4544
#define WF_GDG1 12736
#define WF_BDG1 12800
#define WF_WDG2 12864
#define WF_GDG2 16960
#define WF_BDG2 17024
#define WF_WSN1 17088
#define WF_GSN1 21184
#define WF_BSN1 21248
#define WF_WSN2 21312
#define WF_GSN2 25408
#define WF_BSN2 25472
#define WF_W3 25536
#define WF_G3 29632
#define WF_B3 29696
#define WF_W4 29760
#define WF_G4 37952
#define WF_B4 38080
#define WF_W5 38208
#define WF_G5 103744
#define WF_B5 104256
#define WF_END 104768

__device__ __forceinline__ float lrelu(float x){ return x >= 0.f ? x : 0.01f*x; }

// sortable-uint mapping: preserves float order as unsigned order
__device__ __forceinline__ uint32_t fsort(float v){
  uint32_t b = __float_as_uint(v);
  return b ^ ((uint32_t)((int32_t)b >> 31) | 0x80000000u);
}

// butterfly max over 64 lanes of a u64 key; all lanes end with the global max.
// steps 1,2 = quad_perm DPP; 4,8 = row_ror DPP (reduction-valid rotations); 16,32 = shfl_xor.
#define STEP_DPP(CTRL) { \
    uint32_t olo = (uint32_t)__builtin_amdgcn_update_dpp(0,(int)lo, CTRL, 0xF, 0xF, true); \
    uint32_t ohi = (uint32_t)__builtin_amdgcn_update_dpp(0,(int)hi, CTRL, 0xF, 0xF, true); \
    if (ohi > hi || (ohi == hi && olo > lo)){ hi = ohi; lo = olo; } }
#define STEP_SHFL(MASK) { \
    uint32_t olo = (uint32_t)__shfl_xor((int)lo, MASK, 64); \
    uint32_t ohi = (uint32_t)__shfl_xor((int)hi, MASK, 64); \
    if (ohi > hi || (ohi == hi && olo > lo)){ hi = ohi; lo = olo; } }

__device__ __forceinline__ uint64_t bfly_max_u64(uint64_t k){
  uint32_t lo = (uint32_t)k, hi = (uint32_t)(k >> 32);
  STEP_DPP(0xB1)   // quad_perm [1,0,3,2]  (xor 1)
  STEP_DPP(0x4E)   // quad_perm [2,3,0,1]  (xor 2)
  STEP_DPP(0x124)  // row_ror:4
  STEP_DPP(0x128)  // row_ror:8
  STEP_SHFL(16)
  STEP_SHFL(32)
  return ((uint64_t)hi << 32) | lo;
}

// Iterative exact top-20. row = padded LDS (elem m at (m>>6)*65 + (m&63)).
// K = per-lane segment-max key. MODE 0: owner lane = m&63. MODE 1: owner = (m>>2)&63.
template<int MODE>
__device__ __forceinline__ void topk_iter(const float* __restrict__ row, uint64_t K,
                                          int lane, int* __restrict__ outp){
  uint32_t mlo = 0, mhi = 0;   // consumed mask for this lane's segment
  int keep = 0;
  #pragma unroll 1
  for (int tt = 0; tt < KNN; tt++){
    uint64_t g = bfly_max_u64(K);
    uint32_t m = ~(uint32_t)g;           // winning element index
    keep = (lane == tt) ? (int)m : keep;
    uint32_t js, mre;
    if (MODE == 0){
      js  = m & 63u;
      mre = ((uint32_t)lane << 6) + js;                        // ordinal = lane
    } else {
      js  = (m >> 2) & 63u;
      mre = (((uint32_t)lane >> 2) << 8) + (js << 2) + ((uint32_t)lane & 3u); // ordinal = lane
    }
    uint32_t ord = (MODE == 0) ? (m >> 6) : (((m >> 8) << 2) | (m & 3u));
    if ((uint32_t)lane == js){
      if (ord < 32u) mlo |= 1u << ord; else mhi |= 1u << (ord - 32u);
    }
    int sjs = __builtin_amdgcn_readfirstlane((int)js);
    uint32_t bl = (uint32_t)__builtin_amdgcn_readlane((int)mlo, sjs);
    uint32_t bh = (uint32_t)__builtin_amdgcn_readlane((int)mhi, sjs);
    uint64_t bm = ((uint64_t)bh << 32) | bl;
    uint32_t excl = (uint32_t)((bm >> lane) & 1ull);
    float v = row[(mre >> 6) * 65 + (mre & 63u)];
    uint64_t k2 = ((uint64_t)fsort(v) << 32) | (uint32_t)(~mre);
    if (excl) k2 = 0;
    uint64_t g2 = bfly_max_u64(k2);
    if ((uint32_t)lane == js) K = g2;
  }
  if (lane < KNN) outp[lane] = keep;
}

// ---------------- K-1: dtype detect (1 = fp32 inputs, 0 = bf16) -------------
__global__ void k_detect(const void* __restrict__ x, int* __restrict__ flag){
  int lane = threadIdx.x;
  const bf16* xb = (const bf16*)x;
  int cnt = 0;
  #pragma unroll 1
  for (int i = lane; i < 256; i += 64){
    float v = __bfloat162float(xb[2*i]);      // even elements
    float a = fabsf(v);
    if (a > 1e-3f && a < 100.f) cnt++;
  }
  #pragma unroll
  for (int off = 32; off; off >>= 1) cnt += __shfl_down(cnt, off, 64);
  if (lane == 0) *flag = (cnt >= 128) ? 0 : 1;
}

// ---------------- K0: convert all weights -> fp32 bank ----------------------
struct WPack {
  const void* p[27];
  int off[28];
};

__global__ void k_wcvt(WPack pk, float* __restrict__ dst, const int* __restrict__ flagp){
  int i = blockIdx.x*256 + threadIdx.x;
  if (i >= WF_END) return;
  int f = *flagp;
  #pragma unroll 1
  for (int s = 0; s < 27; s++){
    if (i < pk.off[s+1]){
      int j = i - pk.off[s];
      dst[i] = f ? ((const float*)pk.p[s])[j]
                 : __bfloat162float(((const bf16*)pk.p[s])[j]);
      return;
    }
  }
}

// ---------------- K1: per-point MLP1+MLP2, norms, coords (SoA) --------------
__global__ void k_point(const void* __restrict__ x, float* __restrict__ ws){
  const float* wf = ws + OFF_WF;
  int f = ((const int*)(ws + OFF_FLAG))[0];
  int n = blockIdx.x*256 + threadIdx.x;
  float x0, x1, x2;
  if (f){
    const float* xf = (const float*)x;
    x0 = xf[n*3+0]; x1 = xf[n*3+1]; x2 = xf[n*3+2];
  } else {
    const bf16* xb = (const bf16*)x;
    x0 = __bfloat162float(xb[n*3+0]);
    x1 = __bfloat162float(xb[n*3+1]);
    x2 = __bfloat162float(xb[n*3+2]);
  }

  float h1[64];
  #pragma unroll
  for (int o=0;o<64;o++){
    float a = wf[WF_W1+o*3+0]*x0 + wf[WF_W1+o*3+1]*x1 + wf[WF_W1+o*3+2]*x2;
    h1[o] = lrelu(wf[WF_G1+o]*a + wf[WF_B1+o]);
  }
  float xx = 0.f;
  #pragma unroll 1
  for (int o=0;o<64;o++){
    float a = 0.f;
    #pragma unroll
    for (int c=0;c<64;c++) a += wf[WF_W2+o*64+c]*h1[c];
    float h2 = lrelu(wf[WF_G2+o]*a + wf[WF_B2+o]);
    ws[OFF_H2 + (long)n*64 + o] = h2;
    xx += h2*h2;
  }
  ws[OFF_XX + n] = xx;
  ws[OFF_X + n] = x0; ws[OFF_Y + n] = x1; ws[OFF_Z + n] = x2;
  ws[OFF_XXC + n] = x0*x0 + x1*x1 + x2*x2;
}

// ---------------- K2a: pair GEMM (fp32), per batch chunk --------------------
__global__ __launch_bounds__(256) void k_pair(const float* __restrict__ ws, float* __restrict__ pair,
                                              int b, int n0){
  __shared__ float As[64*128];
  __shared__ float Bs[64*128];
  int t = threadIdx.x;
  int bx = blockIdx.x, by = blockIdx.y;
  const float* h2 = ws + OFF_H2 + (long)b*N_*64;

  int r = t >> 1, c0 = (t & 1)*32;
  const float4* arow = (const float4*)(h2 + (long)(n0 + by*128 + r)*64 + c0);
  const float4* brow = (const float4*)(h2 + (long)(bx*128 + r)*64 + c0);
  #pragma unroll
  for (int q=0;q<8;q++){
    float4 av = arow[q];
    As[(c0+4*q+0)*128 + r] = av.x; As[(c0+4*q+1)*128 + r] = av.y;
    As[(c0+4*q+2)*128 + r] = av.z; As[(c0+4*q+3)*128 + r] = av.w;
    float4 bv = brow[q];
    Bs[(c0+4*q+0)*128 + r] = bv.x; Bs[(c0+4*q+1)*128 + r] = bv.y;
    Bs[(c0+4*q+2)*128 + r] = bv.z; Bs[(c0+4*q+3)*128 + r] = bv.w;
  }
  __syncthreads();

  int tr = t/16, tc = t%16;
  float acc[8][8] = {};
  #pragma unroll 4
  for (int k=0;k<64;k++){
    const float4* ap = (const float4*)&As[k*128 + tr*8];
    const float4* bp = (const float4*)&Bs[k*128 + tc*8];
    float4 a0 = ap[0], a1 = ap[1], c0v = bp[0], c1v = bp[1];
    float a[8] = {a0.x,a0.y,a0.z,a0.w,a1.x,a1.y,a1.z,a1.w};
    float c[8] = {c0v.x,c0v.y,c0v.z,c0v.w,c1v.x,c1v.y,c1v.z,c1v.w};
    #pragma unroll
    for (int i=0;i<8;i++)
      #pragma unroll
      for (int j=0;j<8;j++) acc[i][j] += a[i]*c[j];
  }
  const float* xxp = ws + OFF_XX + b*N_ + bx*128 + tc*8;
  float xxm[8];
  #pragma unroll
  for (int j=0;j<8;j++) xxm[j] = xxp[j];
  #pragma unroll
  for (int i=0;i<8;i++){
    long row = (long)(by*128 + tr*8 + i)*N_ + bx*128 + tc*8;
    float4 o0 = make_float4(2.f*acc[i][0]-xxm[0], 2.f*acc[i][1]-xxm[1],
                            2.f*acc[i][2]-xxm[2], 2.f*acc[i][3]-xxm[3]);
    float4 o1 = make_float4(2.f*acc[i][4]-xxm[4], 2.f*acc[i][5]-xxm[5],
                            2.f*acc[i][6]-xxm[6], 2.f*acc[i][7]-xxm[7]);
    ((float4*)(pair+row))[0] = o0;
    ((float4*)(pair+row))[1] = o1;
  }
}

// ---------------- K2b: top-20 over stored pair rows -------------------------
__global__ __launch_bounds__(64) void k_topk_pair(const float* __restrict__ pair, int* __restrict__ idx1,
                                                  int b, int n0){
  __shared__ float row[4160];
  int lane = threadIdx.x;
  const float4* src = (const float4*)(pair + (long)blockIdx.x*N_);
  float mv = -3.0e38f; uint32_t mi = 0;
  #pragma unroll
  for (int q=0;q<16;q++){
    float4 v = src[lane + 64*q];
    uint32_t m0 = 4u*(uint32_t)lane + 256u*q;
    *(float4*)&row[(m0 >> 6)*65 + (m0 & 63u)] = v;
    if (v.x > mv){ mv = v.x; mi = m0; }
    if (v.y > mv){ mv = v.y; mi = m0+1; }
    if (v.z > mv){ mv = v.z; mi = m0+2; }
    if (v.w > mv){ mv = v.w; mi = m0+3; }
  }
  uint64_t K = ((uint64_t)fsort(mv) << 32) | (uint32_t)(~mi);
  __syncthreads();
  topk_iter<1>(row, K, lane, idx1 + (long)(b*N_ + n0 + blockIdx.x)*KNN);
}

// ---------------- K3: fused coord-space kNN ---------------------------------
__global__ __launch_bounds__(64) void k_knn2(const float* __restrict__ ws, int* __restrict__ idx2){
  __shared__ float row[4160];
  int n = blockIdx.x, lane = threadIdx.x;
  int base = n & ~4095;
  const float* Xp = ws + OFF_X, *Yp = ws + OFF_Y, *Zp = ws + OFF_Z, *Cp = ws + OFF_XXC;
  float xn = Xp[n], yn = Yp[n], zn = Zp[n];
  float mv = -3.0e38f; uint32_t mi = 0;
  #pragma unroll 4
  for (int i=0;i<64;i++){
    int m = i*64 + lane;
    float d = 2.f*(xn*Xp[base+m] + yn*Yp[base+m] + zn*Zp[base+m]) - Cp[base+m];
    row[i*65 + lane] = d;
    if (d > mv){ mv = d; mi = (uint32_t)m; }
  }
  uint64_t K = ((uint64_t)fsort(mv) << 32) | (uint32_t)(~mi);
  __syncthreads();
  topk_iter<0>(row, K, lane, idx2 + (long)n*KNN);
}

// ---------------- K3b: u = (Wa-Wb)h2, v = Wb h2 (post-kNN) ------------------
__global__ void k_uv(float* __restrict__ ws){
  const float* wf = ws + OFF_WF;
  int n = blockIdx.x*256 + threadIdx.x;
  float h[64];
  const float4* src = (const float4*)(ws + OFF_H2 + (long)n*64);
  #pragma unroll
  for (int q=0;q<16;q++){ float4 v = src[q]; h[4*q]=v.x; h[4*q+1]=v.y; h[4*q+2]=v.z; h[4*q+3]=v.w; }
  #pragma unroll 1
  for (int o=0;o<64;o++){
    float va=0.f, vb=0.f;
    #pragma unroll
    for (int c=0;c<64;c++){
      va += wf[WF_WDG1+o*128+c]*h[c];
      vb += wf[WF_WDG1+o*128+64+c]*h[c];
    }
    ws[OFF_U + (long)n*64 + o] = va - vb;
    ws[OFF_V + (long)n*64 + o] = vb;
  }
}

// ---------------- K4/K5: edge stage (gathered first conv folded) ------------
__global__ __launch_bounds__(256) void k_edge(float* __restrict__ ws, const int* __restrict__ idxt,
      int use_u, long uoff, long goff, int w2off,
      int g1off, int b1off, int g2off, int b2off, long outoff){
  __shared__ float y1s[64*65];
  __shared__ float w2s[64*65];
  __shared__ float us [64*65];
  __shared__ float g1s[64], b1s[64], g2s[64], b2s[64];
  const float* wf = ws + OFF_WF;
  int t = threadIdx.x;
  int p0 = blockIdx.x*64;
  int b  = p0 >> 12;

  #pragma unroll 1
  for (int i=t;i<4096;i+=256){ int o = i>>6, kk = i&63; w2s[o*65+kk] = wf[w2off + i]; }
  if (use_u){
    #pragma unroll 1
    for (int i=t;i<4096;i+=256){ int e = i>>6, c = i&63; us[e*65+c] = ws[uoff + (long)(p0+e)*64 + c]; }
  }
  if (t < 64){ g1s[t]=wf[g1off+t]; b1s[t]=wf[b1off+t]; g2s[t]=wf[g2off+t]; b2s[t]=wf[b2off+t]; }
  __syncthreads();

  int lane = t & 63, wv = t >> 6;
  int tr = t & 15, oc = t >> 4;
  float mx[4][4];
  #pragma unroll
  for (int i=0;i<4;i++)
    #pragma unroll
    for (int j=0;j<4;j++) mx[i][j] = -3.0e38f;

  for (int k=0;k<KNN;k++){
    #pragma unroll 4
    for (int jj=0;jj<16;jj++){
      int e  = wv + 4*jj;
      int nb = idxt[(long)(p0+e)*KNN + k];
      float val = ws[goff + ((long)(b<<12) + nb)*64 + lane];
      if (use_u) val += us[e*65 + lane];
      y1s[e*65 + lane] = lrelu(g1s[lane]*val + b1s[lane]);
    }
    __syncthreads();
    float acc[4][4] = {};
    #pragma unroll 4
    for (int kk=0;kk<64;kk++){
      float a0 = y1s[(tr   )*65+kk], a1 = y1s[(tr+16)*65+kk];
      float a2 = y1s[(tr+32)*65+kk], a3 = y1s[(tr+48)*65+kk];
      float c0 = w2s[(oc   )*65+kk], c1 = w2s[(oc+16)*65+kk];
      float c2 = w2s[(oc+32)*65+kk], c3 = w2s[(oc+48)*65+kk];
      acc[0][0]+=a0*c0; acc[0][1]+=a0*c1; acc[0][2]+=a0*c2; acc[0][3]+=a0*c3;
      acc[1][0]+=a1*c0; acc[1][1]+=a1*c1; acc[1][2]+=a1*c2; acc[1][3]+=a1*c3;
      acc[2][0]+=a2*c0; acc[2][1]+=a2*c1; acc[2][2]+=a2*c2; acc[2][3]+=a2*c3;
      acc[3][0]+=a3*c0; acc[3][1]+=a3*c1; acc[3][2]+=a3*c2; acc[3][3]+=a3*c3;
    }
    #pragma unroll
    for (int i=0;i<4;i++)
      #pragma unroll
      for (int j=0;j<4;j++){
        int o = oc + 16*j;
        float yy = lrelu(g2s[o]*acc[i][j] + b2s[o]);
        mx[i][j] = fmaxf(mx[i][j], yy);
      }
    __syncthreads();
  }
  #pragma unroll
  for (int i=0;i<4;i++)
    #pragma unroll
    for (int j=0;j<4;j++)
      ws[outoff + (long)(p0 + tr + 16*i)*64 + oc + 16*j] = mx[i][j];
}

// ---------------- K4b: w = Wsn1 . hdg per point (stored raw) ----------------
__global__ void k_w(float* __restrict__ ws){
  const float* wf = ws + OFF_WF;
  int n = blockIdx.x*256 + threadIdx.x;
  float h[64];
  const float4* src = (const float4*)(ws + OFF_HDG + (long)n*64);
  #pragma unroll
  for (int q=0;q<16;q++){ float4 v = src[q]; h[4*q]=v.x; h[4*q+1]=v.y; h[4*q+2]=v.z; h[4*q+3]=v.w; }
  #pragma unroll 1
  for (int o=0;o<64;o++){
    float a = 0.f;
    #pragma unroll
    for (int c=0;c<64;c++) a += wf[WF_WSN1 + o*64 + c]*h[c];
    ws[OFF_U + (long)n*64 + o] = a;
  }
}

// ---------------- K6: head conv3->conv4->conv5 ------------------------------
__global__ void k_final(const float* __restrict__ ws, void* __restrict__ outv){
  const float* wf = ws + OFF_WF;
  int f = ((const int*)(ws + OFF_FLAG))[0];
  int n = blockIdx.x*256 + threadIdx.x;
  int g = blockIdx.y;
  int b = n >> 12, nn = n & 4095;
  float h[64];
  const float4* src = (const float4*)(ws + OFF_H2 + (long)n*64);
  #pragma unroll
  for (int q=0;q<16;q++){ float4 v = src[q]; h[4*q]=v.x; h[4*q+1]=v.y; h[4*q+2]=v.z; h[4*q+3]=v.w; }
  float h3[64];
  #pragma unroll 1
  for (int o=0;o<64;o++){
    float a = 0.f;
    #pragma unroll
    for (int c=0;c<64;c++) a += wf[WF_W3+o*64+c]*h[c];
    h3[o] = lrelu(wf[WF_G3+o]*a + wf[WF_B3+o]);
  }
  float h4[128];
  #pragma unroll 1
  for (int o=0;o<128;o++){
    float a = 0.f;
    #pragma unroll
    for (int c=0;c<64;c++) a += wf[WF_W4+o*64+c]*h3[c];
    h4[o] = lrelu(wf[WF_G4+o]*a + wf[WF_B4+o]);
  }
  #pragma unroll 1
  for (int o=0;o<128;o++){
    int oo = g*128 + o;
    float a = 0.f;
    #pragma unroll
    for (int c=0;c<128;c++) a += wf[WF_W5 + oo*128 + c]*h4[c];
    a = lrelu(wf[WF_G5+oo]*a + wf[WF_B5+oo]);
    long oi = ((long)(b*512 + oo) << 12) + nn;
    if (f) ((float*)outv)[oi] = a;
    else   ((bf16*)outv)[oi] = __float2bfloat16(a);
  }
}

// ---------------- host ------------------------------------------------------
extern "C" void kernel_launch(void* const* d_in, const int* in_sizes, int n_in,
                              void* d_out, int out_size, void* d_ws, size_t ws_size,
                              hipStream_t stream) {
  const void* X = d_in[0];
  float* ws = (float*)d_ws;
  int* flagp = (int*)(ws + OFF_FLAG);

  WPack pk;
  static const int wsz[27] = {192,64,64, 4096,64,64, 8192,64,64, 4096,64,64, 4096,64,64,
                              4096,64,64, 4096,64,64, 8192,128,128, 65536,512,512};
  int off = 0;
  for (int i=0;i<27;i++){ pk.p[i] = d_in[i+1]; pk.off[i] = off; off += wsz[i]; }
  pk.off[27] = off;

  k_detect<<<dim3(1), dim3(64), 0, stream>>>(X, flagp);
  k_wcvt<<<dim3((WF_END+255)/256), dim3(256), 0, stream>>>(pk, ws + OFF_WF, flagp);
  k_point<<<dim3(NP/256), dim3(256), 0, stream>>>(X, ws);
  k_knn2<<<dim3(NP), dim3(64), 0, stream>>>(ws, (int*)(ws + OFF_IDX2));

  long availf = (long)(ws_size/4) - OFF_PAIR;
  int chunk = 4096;
  if (availf < (long)N_*N_){
    long c = (availf / N_) & ~127L;
    chunk = (int)(c < 128 ? 128 : c);
    if (chunk > 4096) chunk = 4096;
  }
  for (int b=0;b<8;b++){
    for (int n0=0;n0<N_; n0+=chunk){
      int rows = (N_ - n0 < chunk) ? (N_ - n0) : chunk;
      k_pair<<<dim3(32, rows/128), dim3(256), 0, stream>>>(ws, ws + OFF_PAIR, b, n0);
      k_topk_pair<<<dim3(rows), dim3(64), 0, stream>>>(ws + OFF_PAIR, (int*)(ws + OFF_IDX1), b, n0);
    }
  }
  k_uv<<<dim3(NP/256), dim3(256), 0, stream>>>(ws);
  k_edge<<<dim3(NP/64), dim3(256), 0, stream>>>(ws, (const int*)(ws + OFF_IDX1),
        1, OFF_U, OFF_V, WF_WDG2, WF_GDG1, WF_BDG1, WF_GDG2, WF_BDG2, OFF_HDG);
  k_w<<<dim3(NP/256), dim3(256), 0, stream>>>(ws);
  k_edge<<<dim3(NP/64), dim3(256), 0, stream>>>(ws, (const int*)(ws + OFF_IDX2),
        0, 0, OFF_U, WF_WSN2, WF_GSN1, WF_BSN1, WF_GSN2, WF_BSN2, OFF_H2);
  k_final<<<dim3(NP/256, 4), dim3(256), 0, stream>>>(ws, d_out);
}

// Round 4
// 1824.644 us; speedup vs baseline: 1.3677x; 1.1978x over previous
//
#include <hip/hip_runtime.h>
#include <hip/hip_bf16.h>
#include <stdint.h>

typedef __hip_bfloat16 bf16;

#define N_   4096
#define NP   32768   // B*N
#define KNN  20

// ---- workspace layout (units: float) ----
#define OFF_H2   0L         // 32768*64 ; later reused as hsn output
#define OFF_XYZ  2097152L   // 3 planes of 32768 (SoA)
#define OFF_X    2097152L
#define OFF_Y    2129920L
#define OFF_Z    2162688L
#define OFF_XX   2195456L   // 32768  (|h2|^2)
#define OFF_XXC  2228224L   // 32768  (|x|^2)
#define OFF_IDX1 2260992L   // 32768*20 int
#define OFF_IDX2 2916352L   // 32768*20 int
#define OFF_WF   3571712L   // 104768 fp32 weights
#define OFF_FLAG 3676480L   // dtype flag (int), 64-float slot
#define OFF_PAIR 3676544L   // pair chunk lives here during kNN phase
// post-kNN reuse of the pair region:
#define OFF_U    3676544L   // 32768*64 ; u=(Wa-Wb)h2 ; later w = Wsn1*hdg
#define OFF_V    5773696L   // 32768*64 ; v = Wb*h2
#define OFF_HDG  7870848L   // 32768*64
#define OFF_H4   5773696L   // 128*32768 k-major; overlaps V+HDG (both dead by then)

// ---- fp32 weight bank offsets ----
#define WF_W1 0
#define WF_G1 192
#define WF_B1 256
#define WF_W2 320
#define WF_G2 4416
#define WF_B2 4480
#define WF_WDG1 4544
#define WF_GDG1 12736
#define WF_BDG1 12800
#define WF_WDG2 12864
#define WF_GDG2 16960
#define WF_BDG2 17024
#define WF_WSN1 17088
#define WF_GSN1 21184
#define WF_BSN1 21248
#define WF_WSN2 21312
#define WF_GSN2 25408
#define WF_BSN2 25472
#define WF_W3 25536
#define WF_G3 29632
#define WF_B3 29696
#define WF_W4 29760
#define WF_G4 37952
#define WF_B4 38080
#define WF_W5 38208
#define WF_G5 103744
#define WF_B5 104256
#define WF_END 104768

__device__ __forceinline__ float lrelu(float x){ return x >= 0.f ? x : 0.01f*x; }

// sortable-uint mapping: preserves float order as unsigned order
__device__ __forceinline__ uint32_t fsort(float v){
  uint32_t b = __float_as_uint(v);
  return b ^ ((uint32_t)((int32_t)b >> 31) | 0x80000000u);
}

#define STEP_DPP(CTRL) { \
    uint32_t olo = (uint32_t)__builtin_amdgcn_update_dpp(0,(int)lo, CTRL, 0xF, 0xF, true); \
    uint32_t ohi = (uint32_t)__builtin_amdgcn_update_dpp(0,(int)hi, CTRL, 0xF, 0xF, true); \
    if (ohi > hi || (ohi == hi && olo > lo)){ hi = ohi; lo = olo; } }
#define STEP_SHFL(MASK) { \
    uint32_t olo = (uint32_t)__shfl_xor((int)lo, MASK, 64); \
    uint32_t ohi = (uint32_t)__shfl_xor((int)hi, MASK, 64); \
    if (ohi > hi || (ohi == hi && olo > lo)){ hi = ohi; lo = olo; } }

__device__ __forceinline__ uint64_t bfly_max_u64(uint64_t k){
  uint32_t lo = (uint32_t)k, hi = (uint32_t)(k >> 32);
  STEP_DPP(0xB1)   // quad_perm xor1
  STEP_DPP(0x4E)   // quad_perm xor2
  STEP_DPP(0x124)  // row_ror:4
  STEP_DPP(0x128)  // row_ror:8
  STEP_SHFL(16)
  STEP_SHFL(32)
  return ((uint64_t)hi << 32) | lo;
}

// Iterative exact top-20. row = padded LDS (elem m at (m>>6)*65 + (m&63)).
template<int MODE>
__device__ __forceinline__ void topk_iter(const float* __restrict__ row, uint64_t K,
                                          int lane, int* __restrict__ outp){
  uint32_t mlo = 0, mhi = 0;
  int keep = 0;
  #pragma unroll 1
  for (int tt = 0; tt < KNN; tt++){
    uint64_t g = bfly_max_u64(K);
    uint32_t m = ~(uint32_t)g;
    keep = (lane == tt) ? (int)m : keep;
    uint32_t js, mre;
    if (MODE == 0){
      js  = m & 63u;
      mre = ((uint32_t)lane << 6) + js;
    } else {
      js  = (m >> 2) & 63u;
      mre = (((uint32_t)lane >> 2) << 8) + (js << 2) + ((uint32_t)lane & 3u);
    }
    uint32_t ord = (MODE == 0) ? (m >> 6) : (((m >> 8) << 2) | (m & 3u));
    if ((uint32_t)lane == js){
      if (ord < 32u) mlo |= 1u << ord; else mhi |= 1u << (ord - 32u);
    }
    int sjs = __builtin_amdgcn_readfirstlane((int)js);
    uint32_t bl = (uint32_t)__builtin_amdgcn_readlane((int)mlo, sjs);
    uint32_t bh = (uint32_t)__builtin_amdgcn_readlane((int)mhi, sjs);
    uint64_t bm = ((uint64_t)bh << 32) | bl;
    uint32_t excl = (uint32_t)((bm >> lane) & 1ull);
    float v = row[(mre >> 6) * 65 + (mre & 63u)];
    uint64_t k2 = ((uint64_t)fsort(v) << 32) | (uint32_t)(~mre);
    if (excl) k2 = 0;
    uint64_t g2 = bfly_max_u64(k2);
    if ((uint32_t)lane == js) K = g2;
  }
  if (lane < KNN) outp[lane] = keep;
}

// ---------------- K-1: dtype detect (1 = fp32 inputs, 0 = bf16) -------------
__global__ void k_detect(const void* __restrict__ x, int* __restrict__ flag){
  int lane = threadIdx.x;
  const bf16* xb = (const bf16*)x;
  int cnt = 0;
  #pragma unroll 1
  for (int i = lane; i < 256; i += 64){
    float v = __bfloat162float(xb[2*i]);
    float a = fabsf(v);
    if (a > 1e-3f && a < 100.f) cnt++;
  }
  #pragma unroll
  for (int off = 32; off; off >>= 1) cnt += __shfl_down(cnt, off, 64);
  if (lane == 0) *flag = (cnt >= 128) ? 0 : 1;
}

// ---------------- K0: convert all weights -> fp32 bank ----------------------
struct WPack {
  const void* p[27];
  int off[28];
};

__global__ void k_wcvt(WPack pk, float* __restrict__ dst, const int* __restrict__ flagp){
  int i = blockIdx.x*256 + threadIdx.x;
  if (i >= WF_END) return;
  int f = *flagp;
  #pragma unroll 1
  for (int s = 0; s < 27; s++){
    if (i < pk.off[s+1]){
      int j = i - pk.off[s];
      dst[i] = f ? ((const float*)pk.p[s])[j]
                 : __bfloat162float(((const bf16*)pk.p[s])[j]);
      return;
    }
  }
}

// ---------------- K1: per-point MLP1+MLP2, norms, coords (SoA) --------------
__global__ void k_point(const void* __restrict__ x, float* __restrict__ ws){
  const float* wf = ws + OFF_WF;
  int f = ((const int*)(ws + OFF_FLAG))[0];
  int n = blockIdx.x*256 + threadIdx.x;
  float x0, x1, x2;
  if (f){
    const float* xf = (const float*)x;
    x0 = xf[n*3+0]; x1 = xf[n*3+1]; x2 = xf[n*3+2];
  } else {
    const bf16* xb = (const bf16*)x;
    x0 = __bfloat162float(xb[n*3+0]);
    x1 = __bfloat162float(xb[n*3+1]);
    x2 = __bfloat162float(xb[n*3+2]);
  }

  float h1[64];
  #pragma unroll
  for (int o=0;o<64;o++){
    float a = wf[WF_W1+o*3+0]*x0 + wf[WF_W1+o*3+1]*x1 + wf[WF_W1+o*3+2]*x2;
    h1[o] = lrelu(wf[WF_G1+o]*a + wf[WF_B1+o]);
  }
  float xx = 0.f;
  #pragma unroll 1
  for (int o=0;o<64;o++){
    float a = 0.f;
    #pragma unroll
    for (int c=0;c<64;c++) a += wf[WF_W2+o*64+c]*h1[c];
    float h2 = lrelu(wf[WF_G2+o]*a + wf[WF_B2+o]);
    ws[OFF_H2 + (long)n*64 + o] = h2;
    xx += h2*h2;
  }
  ws[OFF_XX + n] = xx;
  ws[OFF_X + n] = x0; ws[OFF_Y + n] = x1; ws[OFF_Z + n] = x2;
  ws[OFF_XXC + n] = x0*x0 + x1*x1 + x2*x2;
}

// ---------------- K2a: pair GEMM (fp32), per batch chunk --------------------
__global__ __launch_bounds__(256) void k_pair(const float* __restrict__ ws, float* __restrict__ pair,
                                              int b, int n0){
  __shared__ float As[64*128];
  __shared__ float Bs[64*128];
  int t = threadIdx.x;
  int bx = blockIdx.x, by = blockIdx.y;
  const float* h2 = ws + OFF_H2 + (long)b*N_*64;

  int r = t >> 1, c0 = (t & 1)*32;
  const float4* arow = (const float4*)(h2 + (long)(n0 + by*128 + r)*64 + c0);
  const float4* brow = (const float4*)(h2 + (long)(bx*128 + r)*64 + c0);
  #pragma unroll
  for (int q=0;q<8;q++){
    float4 av = arow[q];
    As[(c0+4*q+0)*128 + r] = av.x; As[(c0+4*q+1)*128 + r] = av.y;
    As[(c0+4*q+2)*128 + r] = av.z; As[(c0+4*q+3)*128 + r] = av.w;
    float4 bv = brow[q];
    Bs[(c0+4*q+0)*128 + r] = bv.x; Bs[(c0+4*q+1)*128 + r] = bv.y;
    Bs[(c0+4*q+2)*128 + r] = bv.z; Bs[(c0+4*q+3)*128 + r] = bv.w;
  }
  __syncthreads();

  int tr = t/16, tc = t%16;
  float acc[8][8] = {};
  #pragma unroll 4
  for (int k=0;k<64;k++){
    const float4* ap = (const float4*)&As[k*128 + tr*8];
    const float4* bp = (const float4*)&Bs[k*128 + tc*8];
    float4 a0 = ap[0], a1 = ap[1], c0v = bp[0], c1v = bp[1];
    float a[8] = {a0.x,a0.y,a0.z,a0.w,a1.x,a1.y,a1.z,a1.w};
    float c[8] = {c0v.x,c0v.y,c0v.z,c0v.w,c1v.x,c1v.y,c1v.z,c1v.w};
    #pragma unroll
    for (int i=0;i<8;i++)
      #pragma unroll
      for (int j=0;j<8;j++) acc[i][j] += a[i]*c[j];
  }
  const float* xxp = ws + OFF_XX + b*N_ + bx*128 + tc*8;
  float xxm[8];
  #pragma unroll
  for (int j=0;j<8;j++) xxm[j] = xxp[j];
  #pragma unroll
  for (int i=0;i<8;i++){
    long row = (long)(by*128 + tr*8 + i)*N_ + bx*128 + tc*8;
    float4 o0 = make_float4(2.f*acc[i][0]-xxm[0], 2.f*acc[i][1]-xxm[1],
                            2.f*acc[i][2]-xxm[2], 2.f*acc[i][3]-xxm[3]);
    float4 o1 = make_float4(2.f*acc[i][4]-xxm[4], 2.f*acc[i][5]-xxm[5],
                            2.f*acc[i][6]-xxm[6], 2.f*acc[i][7]-xxm[7]);
    ((float4*)(pair+row))[0] = o0;
    ((float4*)(pair+row))[1] = o1;
  }
}

// ---------------- K2b: top-20 over stored pair rows -------------------------
__global__ __launch_bounds__(64) void k_topk_pair(const float* __restrict__ pair, int* __restrict__ idx1,
                                                  int b, int n0){
  __shared__ float row[4160];
  int lane = threadIdx.x;
  const float4* src = (const float4*)(pair + (long)blockIdx.x*N_);
  float mv = -3.0e38f; uint32_t mi = 0;
  #pragma unroll
  for (int q=0;q<16;q++){
    float4 v = src[lane + 64*q];
    uint32_t m0 = 4u*(uint32_t)lane + 256u*q;
    *(float4*)&row[(m0 >> 6)*65 + (m0 & 63u)] = v;
    if (v.x > mv){ mv = v.x; mi = m0; }
    if (v.y > mv){ mv = v.y; mi = m0+1; }
    if (v.z > mv){ mv = v.z; mi = m0+2; }
    if (v.w > mv){ mv = v.w; mi = m0+3; }
  }
  uint64_t K = ((uint64_t)fsort(mv) << 32) | (uint32_t)(~mi);
  __syncthreads();
  topk_iter<1>(row, K, lane, idx1 + (long)(b*N_ + n0 + blockIdx.x)*KNN);
}

// ---------------- K3: fused coord-space kNN ---------------------------------
__global__ __launch_bounds__(64) void k_knn2(const float* __restrict__ ws, int* __restrict__ idx2){
  __shared__ float row[4160];
  int n = blockIdx.x, lane = threadIdx.x;
  int base = n & ~4095;
  const float* Xp = ws + OFF_X, *Yp = ws + OFF_Y, *Zp = ws + OFF_Z, *Cp = ws + OFF_XXC;
  float xn = Xp[n], yn = Yp[n], zn = Zp[n];
  float mv = -3.0e38f; uint32_t mi = 0;
  #pragma unroll 4
  for (int i=0;i<64;i++){
    int m = i*64 + lane;
    float d = 2.f*(xn*Xp[base+m] + yn*Yp[base+m] + zn*Zp[base+m]) - Cp[base+m];
    row[i*65 + lane] = d;
    if (d > mv){ mv = d; mi = (uint32_t)m; }
  }
  uint64_t K = ((uint64_t)fsort(mv) << 32) | (uint32_t)(~mi);
  __syncthreads();
  topk_iter<0>(row, K, lane, idx2 + (long)n*KNN);
}

// ---------------- K3b: u = (Wa-Wb)h2, v = Wb h2 (post-kNN) ------------------
__global__ void k_uv(float* __restrict__ ws){
  const float* wf = ws + OFF_WF;
  int n = blockIdx.x*256 + threadIdx.x;
  float h[64];
  const float4* src = (const float4*)(ws + OFF_H2 + (long)n*64);
  #pragma unroll
  for (int q=0;q<16;q++){ float4 v = src[q]; h[4*q]=v.x; h[4*q+1]=v.y; h[4*q+2]=v.z; h[4*q+3]=v.w; }
  #pragma unroll 1
  for (int o=0;o<64;o++){
    float va=0.f, vb=0.f;
    #pragma unroll
    for (int c=0;c<64;c++){
      va += wf[WF_WDG1+o*128+c]*h[c];
      vb += wf[WF_WDG1+o*128+64+c]*h[c];
    }
    ws[OFF_U + (long)n*64 + o] = va - vb;
    ws[OFF_V + (long)n*64 + o] = vb;
  }
}

// ---------------- K4/K5: edge stage (gathered first conv folded) ------------
__global__ __launch_bounds__(256) void k_edge(float* __restrict__ ws, const int* __restrict__ idxt,
      int use_u, long uoff, long goff, int w2off,
      int g1off, int b1off, int g2off, int b2off, long outoff){
  __shared__ float y1s[64*65];
  __shared__ float w2s[64*65];
  __shared__ float us [64*65];
  __shared__ float g1s[64], b1s[64], g2s[64], b2s[64];
  const float* wf = ws + OFF_WF;
  int t = threadIdx.x;
  int p0 = blockIdx.x*64;
  int b  = p0 >> 12;

  #pragma unroll 1
  for (int i=t;i<4096;i+=256){ int o = i>>6, kk = i&63; w2s[o*65+kk] = wf[w2off + i]; }
  if (use_u){
    #pragma unroll 1
    for (int i=t;i<4096;i+=256){ int e = i>>6, c = i&63; us[e*65+c] = ws[uoff + (long)(p0+e)*64 + c]; }
  }
  if (t < 64){ g1s[t]=wf[g1off+t]; b1s[t]=wf[b1off+t]; g2s[t]=wf[g2off+t]; b2s[t]=wf[b2off+t]; }
  __syncthreads();

  int lane = t & 63, wv = t >> 6;
  int tr = t & 15, oc = t >> 4;
  float mx[4][4];
  #pragma unroll
  for (int i=0;i<4;i++)
    #pragma unroll
    for (int j=0;j<4;j++) mx[i][j] = -3.0e38f;

  for (int k=0;k<KNN;k++){
    #pragma unroll 4
    for (int jj=0;jj<16;jj++){
      int e  = wv + 4*jj;
      int nb = idxt[(long)(p0+e)*KNN + k];
      float val = ws[goff + ((long)(b<<12) + nb)*64 + lane];
      if (use_u) val += us[e*65 + lane];
      y1s[e*65 + lane] = lrelu(g1s[lane]*val + b1s[lane]);
    }
    __syncthreads();
    float acc[4][4] = {};
    #pragma unroll 4
    for (int kk=0;kk<64;kk++){
      float a0 = y1s[(tr   )*65+kk], a1 = y1s[(tr+16)*65+kk];
      float a2 = y1s[(tr+32)*65+kk], a3 = y1s[(tr+48)*65+kk];
      float c0 = w2s[(oc   )*65+kk], c1 = w2s[(oc+16)*65+kk];
      float c2 = w2s[(oc+32)*65+kk], c3 = w2s[(oc+48)*65+kk];
      acc[0][0]+=a0*c0; acc[0][1]+=a0*c1; acc[0][2]+=a0*c2; acc[0][3]+=a0*c3;
      acc[1][0]+=a1*c0; acc[1][1]+=a1*c1; acc[1][2]+=a1*c2; acc[1][3]+=a1*c3;
      acc[2][0]+=a2*c0; acc[2][1]+=a2*c1; acc[2][2]+=a2*c2; acc[2][3]+=a2*c3;
      acc[3][0]+=a3*c0; acc[3][1]+=a3*c1; acc[3][2]+=a3*c2; acc[3][3]+=a3*c3;
    }
    #pragma unroll
    for (int i=0;i<4;i++)
      #pragma unroll
      for (int j=0;j<4;j++){
        int o = oc + 16*j;
        float yy = lrelu(g2s[o]*acc[i][j] + b2s[o]);
        mx[i][j] = fmaxf(mx[i][j], yy);
      }
    __syncthreads();
  }
  #pragma unroll
  for (int i=0;i<4;i++)
    #pragma unroll
    for (int j=0;j<4;j++)
      ws[outoff + (long)(p0 + tr + 16*i)*64 + oc + 16*j] = mx[i][j];
}

// ---------------- K4b: w = Wsn1 . hdg per point (stored raw) ----------------
__global__ void k_w(float* __restrict__ ws){
  const float* wf = ws + OFF_WF;
  int n = blockIdx.x*256 + threadIdx.x;
  float h[64];
  const float4* src = (const float4*)(ws + OFF_HDG + (long)n*64);
  #pragma unroll
  for (int q=0;q<16;q++){ float4 v = src[q]; h[4*q]=v.x; h[4*q+1]=v.y; h[4*q+2]=v.z; h[4*q+3]=v.w; }
  #pragma unroll 1
  for (int o=0;o<64;o++){
    float a = 0.f;
    #pragma unroll
    for (int c=0;c<64;c++) a += wf[WF_WSN1 + o*64 + c]*h[c];
    ws[OFF_U + (long)n*64 + o] = a;
  }
}

// ---------------- K6a: head conv3+conv4, h4 out in k-major [128][NP] --------
__global__ __launch_bounds__(256) void k_h4(const float* __restrict__ ws, float* __restrict__ h4g){
  __shared__ float Hs[64*65];    // [ch][pt] (hsn), then reused as [o3][pt] (h3)
  __shared__ float wb[64*130];   // W3 as wb[c*65+o]; later W4 as wb[c*130+o]
  const float* wf = ws + OFF_WF;
  int t = threadIdx.x;
  int p0 = blockIdx.x*64;

  // load hsn tile transposed: [pt][64] -> Hs[ch][pt]
  {
    int r = t >> 2, c0 = (t & 3)*16;
    const float4* src = (const float4*)(ws + OFF_H2 + (long)(p0 + r)*64 + c0);
    #pragma unroll
    for (int q=0;q<4;q++){
      float4 v = src[q];
      Hs[(c0+4*q+0)*65 + r] = v.x; Hs[(c0+4*q+1)*65 + r] = v.y;
      Hs[(c0+4*q+2)*65 + r] = v.z; Hs[(c0+4*q+3)*65 + r] = v.w;
    }
  }
  // load W3 [64][64] transposed -> wb[c*65+o]
  {
    int r = t >> 2, c0 = (t & 3)*16;
    const float4* src = (const float4*)(wf + WF_W3 + (long)r*64 + c0);
    #pragma unroll
    for (int q=0;q<4;q++){
      float4 v = src[q];
      wb[(c0+4*q+0)*65 + r] = v.x; wb[(c0+4*q+1)*65 + r] = v.y;
      wb[(c0+4*q+2)*65 + r] = v.z; wb[(c0+4*q+3)*65 + r] = v.w;
    }
  }
  __syncthreads();

  int pr = t & 15, og = t >> 4;   // pts pr*4..+3 ; conv3 outs og*4..+3
  float acc[4][4] = {};
  #pragma unroll 8
  for (int k=0;k<64;k++){
    float4 a = *(const float4*)&Hs[k*65 + pr*4];
    float4 c = *(const float4*)&wb[k*65 + og*4];
    float av[4] = {a.x,a.y,a.z,a.w}, cv[4] = {c.x,c.y,c.z,c.w};
    #pragma unroll
    for (int i=0;i<4;i++)
      #pragma unroll
      for (int j=0;j<4;j++) acc[i][j] += av[i]*cv[j];
  }
  __syncthreads();   // all reads of Hs/wb done

  // h3 = bn+lrelu -> Hs[o][pt]
  #pragma unroll
  for (int j=0;j<4;j++){
    int o = og*4 + j;
    float g3 = wf[WF_G3+o], b3 = wf[WF_B3+o];
    #pragma unroll
    for (int i=0;i<4;i++)
      Hs[o*65 + pr*4 + i] = lrelu(g3*acc[i][j] + b3);
  }
  // load W4 [128][64] transposed -> wb[c*130+o]
  {
    int r = t >> 1, c0 = (t & 1)*32;
    const float4* src = (const float4*)(wf + WF_W4 + (long)r*64 + c0);
    #pragma unroll
    for (int q=0;q<8;q++){
      float4 v = src[q];
      wb[(c0+4*q+0)*130 + r] = v.x; wb[(c0+4*q+1)*130 + r] = v.y;
      wb[(c0+4*q+2)*130 + r] = v.z; wb[(c0+4*q+3)*130 + r] = v.w;
    }
  }
  __syncthreads();

  // conv4: outs og*8..+7
  float a2[4][8] = {};
  #pragma unroll 8
  for (int k=0;k<64;k++){
    float4 a = *(const float4*)&Hs[k*65 + pr*4];
    float4 c0 = *(const float4*)&wb[k*130 + og*8];
    float4 c1 = *(const float4*)&wb[k*130 + og*8 + 4];
    float av[4] = {a.x,a.y,a.z,a.w};
    float cv[8] = {c0.x,c0.y,c0.z,c0.w,c1.x,c1.y,c1.z,c1.w};
    #pragma unroll
    for (int i=0;i<4;i++)
      #pragma unroll
      for (int j=0;j<8;j++) a2[i][j] += av[i]*cv[j];
  }
  #pragma unroll
  for (int j=0;j<8;j++){
    int o = og*8 + j;
    float g4 = wf[WF_G4+o], b4 = wf[WF_B4+o];
    #pragma unroll
    for (int i=0;i<4;i++)
      h4g[(long)o*NP + p0 + pr*4 + i] = lrelu(g4*a2[i][j] + b4);
  }
}

// ---------------- K6b: conv5 GEMM [512 x 128] . [128 x NP] ------------------
#define KC 32
__global__ __launch_bounds__(256) void k_conv5(const float* __restrict__ ws, void* __restrict__ outv){
  __shared__ float As[KC*128];   // [k][o]
  __shared__ float Bs[KC*128];   // [k][pt]
  const float* wf = ws + OFF_WF;
  int f = ((const int*)(ws + OFF_FLAG))[0];
  int t = threadIdx.x;
  int p0 = blockIdx.x*128;
  int o0 = blockIdx.y*128;
  const float* H4 = ws + OFF_H4;
  float acc[8][8] = {};

  for (int kc = 0; kc < 128; kc += KC){
    {
      int r = t >> 1, c0 = (t & 1)*16;
      const float4* src = (const float4*)(wf + WF_W5 + (long)(o0 + r)*128 + kc + c0);
      #pragma unroll
      for (int q=0;q<4;q++){
        float4 v = src[q];
        As[(c0+4*q+0)*128 + r] = v.x; As[(c0+4*q+1)*128 + r] = v.y;
        As[(c0+4*q+2)*128 + r] = v.z; As[(c0+4*q+3)*128 + r] = v.w;
      }
    }
    {
      int kr = t >> 3, pc = (t & 7)*16;
      const float4* src = (const float4*)(H4 + (long)(kc + kr)*NP + p0 + pc);
      float4 v0 = src[0], v1 = src[1], v2 = src[2], v3 = src[3];
      *(float4*)&Bs[kr*128 + pc     ] = v0;
      *(float4*)&Bs[kr*128 + pc + 4 ] = v1;
      *(float4*)&Bs[kr*128 + pc + 8 ] = v2;
      *(float4*)&Bs[kr*128 + pc + 12] = v3;
    }
    __syncthreads();
    int tr = t/16, tc = t%16;
    #pragma unroll 8
    for (int k=0;k<KC;k++){
      const float4* ap = (const float4*)&As[k*128 + tr*8];
      const float4* bp = (const float4*)&Bs[k*128 + tc*8];
      float4 a0 = ap[0], a1 = ap[1], b0 = bp[0], b1 = bp[1];
      float a[8] = {a0.x,a0.y,a0.z,a0.w,a1.x,a1.y,a1.z,a1.w};
      float b[8] = {b0.x,b0.y,b0.z,b0.w,b1.x,b1.y,b1.z,b1.w};
      #pragma unroll
      for (int i=0;i<8;i++)
        #pragma unroll
        for (int j=0;j<8;j++) acc[i][j] += a[i]*b[j];
    }
    __syncthreads();
  }

  int tr = t/16, tc = t%16;
  int b = p0 >> 12, nn = (p0 & 4095) + tc*8;
  #pragma unroll
  for (int i=0;i<8;i++){
    int oo = o0 + tr*8 + i;
    float g5 = wf[WF_G5+oo], b5 = wf[WF_B5+oo];
    long base = ((long)(b*512 + oo) << 12) + nn;
    if (f){
      float4 v0 = make_float4(lrelu(g5*acc[i][0]+b5), lrelu(g5*acc[i][1]+b5),
                              lrelu(g5*acc[i][2]+b5), lrelu(g5*acc[i][3]+b5));
      float4 v1 = make_float4(lrelu(g5*acc[i][4]+b5), lrelu(g5*acc[i][5]+b5),
                              lrelu(g5*acc[i][6]+b5), lrelu(g5*acc[i][7]+b5));
      *(float4*)((float*)outv + base)     = v0;
      *(float4*)((float*)outv + base + 4) = v1;
    } else {
      #pragma unroll
      for (int j=0;j<8;j++)
        ((bf16*)outv)[base + j] = __float2bfloat16(lrelu(g5*acc[i][j] + b5));
    }
  }
}

// ---------------- host ------------------------------------------------------
extern "C" void kernel_launch(void* const* d_in, const int* in_sizes, int n_in,
                              void* d_out, int out_size, void* d_ws, size_t ws_size,
                              hipStream_t stream) {
  const void* X = d_in[0];
  float* ws = (float*)d_ws;
  int* flagp = (int*)(ws + OFF_FLAG);

  WPack pk;
  static const int wsz[27] = {192,64,64, 4096,64,64, 8192,64,64, 4096,64,64, 4096,64,64,
                              4096,64,64, 4096,64,64, 8192,128,128, 65536,512,512};
  int off = 0;
  for (int i=0;i<27;i++){ pk.p[i] = d_in[i+1]; pk.off[i] = off; off += wsz[i]; }
  pk.off[27] = off;

  k_detect<<<dim3(1), dim3(64), 0, stream>>>(X, flagp);
  k_wcvt<<<dim3((WF_END+255)/256), dim3(256), 0, stream>>>(pk, ws + OFF_WF, flagp);
  k_point<<<dim3(NP/256), dim3(256), 0, stream>>>(X, ws);
  k_knn2<<<dim3(NP), dim3(64), 0, stream>>>(ws, (int*)(ws + OFF_IDX2));

  long availf = (long)(ws_size/4) - OFF_PAIR;
  int chunk = 4096;
  if (availf < (long)N_*N_){
    long c = (availf / N_) & ~127L;
    chunk = (int)(c < 128 ? 128 : c);
    if (chunk > 4096) chunk = 4096;
  }
  for (int b=0;b<8;b++){
    for (int n0=0;n0<N_; n0+=chunk){
      int rows = (N_ - n0 < chunk) ? (N_ - n0) : chunk;
      k_pair<<<dim3(32, rows/128), dim3(256), 0, stream>>>(ws, ws + OFF_PAIR, b, n0);
      k_topk_pair<<<dim3(rows), dim3(64), 0, stream>>>(ws + OFF_PAIR, (int*)(ws + OFF_IDX1), b, n0);
    }
  }
  k_uv<<<dim3(NP/256), dim3(256), 0, stream>>>(ws);
  k_edge<<<dim3(NP/64), dim3(256), 0, stream>>>(ws, (const int*)(ws + OFF_IDX1),
        1, OFF_U, OFF_V, WF_WDG2, WF_GDG1, WF_BDG1, WF_GDG2, WF_BDG2, OFF_HDG);
  k_w<<<dim3(NP/256), dim3(256), 0, stream>>>(ws);
  k_edge<<<dim3(NP/64), dim3(256), 0, stream>>>(ws, (const int*)(ws + OFF_IDX2),
        0, 0, OFF_U, WF_WSN2, WF_GSN1, WF_BSN1, WF_GSN2, WF_BSN2, OFF_H2);
  k_h4<<<dim3(NP/64), dim3(256), 0, stream>>>(ws, ws + OFF_H4);
  k_conv5<<<dim3(NP/128, 4), dim3(256), 0, stream>>>(ws, d_out);
}

// Round 5
// 1538.657 us; speedup vs baseline: 1.6219x; 1.1859x over previous
//
#include <hip/hip_runtime.h>
#include <hip/hip_bf16.h>
#include <stdint.h>

typedef __hip_bfloat16 bf16;

#define N_   4096
#define NP   32768   // B*N
#define KNN  20

// ---- workspace layout (units: float) ----
#define OFF_H2   0L         // 32768*64 ; later reused as hsn output
#define OFF_XYZ  2097152L   // 3 planes of 32768 (SoA)
#define OFF_X    2097152L
#define OFF_Y    2129920L
#define OFF_Z    2162688L
#define OFF_XX   2195456L   // 32768  (|h2|^2)
#define OFF_XXC  2228224L   // 32768  (|x|^2)
#define OFF_IDX1 2260992L   // 32768*20 int
#define OFF_IDX2 2916352L   // 32768*20 int
#define OFF_WF   3571712L   // 104768 fp32 weights
#define OFF_FLAG 3676480L   // dtype flag (int), 64-float slot
#define OFF_PAIR 3676544L   // pair chunk lives here during kNN phase
// post-kNN reuse of the pair region:
#define OFF_U    3676544L   // 32768*64 ; u=(Wa-Wb)h2 ; later w = Wsn1*hdg
#define OFF_V    5773696L   // 32768*64 ; v = Wb*h2
#define OFF_HDG  7870848L   // 32768*64
#define OFF_H4   5773696L   // 128*32768 k-major; overlaps V+HDG (both dead by then)

// ---- fp32 weight bank offsets ----
#define WF_W1 0
#define WF_G1 192
#define WF_B1 256
#define WF_W2 320
#define WF_G2 4416
#define WF_B2 4480
#define WF_WDG1 4544
#define WF_GDG1 12736
#define WF_BDG1 12800
#define WF_WDG2 12864
#define WF_GDG2 16960
#define WF_BDG2 17024
#define WF_WSN1 17088
#define WF_GSN1 21184
#define WF_BSN1 21248
#define WF_WSN2 21312
#define WF_GSN2 25408
#define WF_BSN2 25472
#define WF_W3 25536
#define WF_G3 29632
#define WF_B3 29696
#define WF_W4 29760
#define WF_G4 37952
#define WF_B4 38080
#define WF_W5 38208
#define WF_G5 103744
#define WF_B5 104256
#define WF_END 104768

__device__ __forceinline__ float lrelu(float x){ return x >= 0.f ? x : 0.01f*x; }

// sortable-uint mapping: preserves float order as unsigned order
__device__ __forceinline__ uint32_t fsort(float v){
  uint32_t b = __float_as_uint(v);
  return b ^ ((uint32_t)((int32_t)b >> 31) | 0x80000000u);
}

// butterfly max over 64 lanes of a u64 key (packed compare: v_cmp_lt_u64 + 2 cndmask)
#define BSTEP_DPP(CTRL) { \
    uint32_t olo = (uint32_t)__builtin_amdgcn_update_dpp(0,(int)(uint32_t)k, CTRL, 0xF, 0xF, true); \
    uint32_t ohi = (uint32_t)__builtin_amdgcn_update_dpp(0,(int)(uint32_t)(k>>32), CTRL, 0xF, 0xF, true); \
    uint64_t o = ((uint64_t)ohi << 32) | olo; \
    if (o > k) k = o; }
#define BSTEP_SHFL(MASK) { \
    uint32_t olo = (uint32_t)__shfl_xor((int)(uint32_t)k, MASK, 64); \
    uint32_t ohi = (uint32_t)__shfl_xor((int)(uint32_t)(k>>32), MASK, 64); \
    uint64_t o = ((uint64_t)ohi << 32) | olo; \
    if (o > k) k = o; }

__device__ __forceinline__ uint64_t bfly_max_u64(uint64_t k){
  BSTEP_DPP(0xB1)   // quad_perm xor1
  BSTEP_DPP(0x4E)   // quad_perm xor2
  BSTEP_DPP(0x124)  // row_ror:4
  BSTEP_DPP(0x128)  // row_ror:8
  BSTEP_SHFL(16)
  BSTEP_SHFL(32)
  return k;
}

// Iterative exact top-20. row = padded LDS (elem m at (m>>6)*65 + (m&63)).
// K = per-lane segment-max key. MODE 0: owner lane = m&63. MODE 1: owner = (m>>2)&63.
template<int MODE>
__device__ __forceinline__ void topk_iter(const float* __restrict__ row, uint64_t K,
                                          int lane, int* __restrict__ outp){
  uint32_t mlo = 0, mhi = 0;
  int keep = 0;
  #pragma unroll 1
  for (int tt = 0; tt < KNN; tt++){
    uint64_t g = bfly_max_u64(K);
    uint32_t m = ~(uint32_t)g;
    keep = (lane == tt) ? (int)m : keep;
    uint32_t js, mre;
    if (MODE == 0){
      js  = m & 63u;
      mre = ((uint32_t)lane << 6) + js;
    } else {
      js  = (m >> 2) & 63u;
      mre = (((uint32_t)lane >> 2) << 8) + (js << 2) + ((uint32_t)lane & 3u);
    }
    uint32_t ord = (MODE == 0) ? (m >> 6) : (((m >> 8) << 2) | (m & 3u));
    if ((uint32_t)lane == js){
      if (ord < 32u) mlo |= 1u << ord; else mhi |= 1u << (ord - 32u);
    }
    int sjs = __builtin_amdgcn_readfirstlane((int)js);
    uint32_t bl = (uint32_t)__builtin_amdgcn_readlane((int)mlo, sjs);
    uint32_t bh = (uint32_t)__builtin_amdgcn_readlane((int)mhi, sjs);
    uint64_t bm = ((uint64_t)bh << 32) | bl;
    uint32_t excl = (uint32_t)((bm >> lane) & 1ull);
    float v = row[(mre >> 6) * 65 + (mre & 63u)];
    uint64_t k2 = ((uint64_t)fsort(v) << 32) | (uint32_t)(~mre);
    if (excl) k2 = 0;
    uint64_t g2 = bfly_max_u64(k2);
    if ((uint32_t)lane == js) K = g2;
  }
  if (lane < KNN) outp[lane] = keep;
}

// ---------------- K-1: dtype detect (1 = fp32 inputs, 0 = bf16) -------------
__global__ void k_detect(const void* __restrict__ x, int* __restrict__ flag){
  int lane = threadIdx.x;
  const bf16* xb = (const bf16*)x;
  int cnt = 0;
  #pragma unroll 1
  for (int i = lane; i < 256; i += 64){
    float v = __bfloat162float(xb[2*i]);
    float a = fabsf(v);
    if (a > 1e-3f && a < 100.f) cnt++;
  }
  #pragma unroll
  for (int off = 32; off; off >>= 1) cnt += __shfl_down(cnt, off, 64);
  if (lane == 0) *flag = (cnt >= 128) ? 0 : 1;
}

// ---------------- K0: convert all weights -> fp32 bank ----------------------
struct WPack {
  const void* p[27];
  int off[28];
};

__global__ void k_wcvt(WPack pk, float* __restrict__ dst, const int* __restrict__ flagp){
  int i = blockIdx.x*256 + threadIdx.x;
  if (i >= WF_END) return;
  int f = *flagp;
  #pragma unroll 1
  for (int s = 0; s < 27; s++){
    if (i < pk.off[s+1]){
      int j = i - pk.off[s];
      dst[i] = f ? ((const float*)pk.p[s])[j]
                 : __bfloat162float(((const bf16*)pk.p[s])[j]);
      return;
    }
  }
}

// ---------------- K1: per-point MLP1+MLP2, norms, coords (SoA) --------------
__global__ void k_point(const void* __restrict__ x, float* __restrict__ ws){
  const float* wf = ws + OFF_WF;
  int f = ((const int*)(ws + OFF_FLAG))[0];
  int n = blockIdx.x*256 + threadIdx.x;
  float x0, x1, x2;
  if (f){
    const float* xf = (const float*)x;
    x0 = xf[n*3+0]; x1 = xf[n*3+1]; x2 = xf[n*3+2];
  } else {
    const bf16* xb = (const bf16*)x;
    x0 = __bfloat162float(xb[n*3+0]);
    x1 = __bfloat162float(xb[n*3+1]);
    x2 = __bfloat162float(xb[n*3+2]);
  }

  float h1[64];
  #pragma unroll
  for (int o=0;o<64;o++){
    float a = wf[WF_W1+o*3+0]*x0 + wf[WF_W1+o*3+1]*x1 + wf[WF_W1+o*3+2]*x2;
    h1[o] = lrelu(wf[WF_G1+o]*a + wf[WF_B1+o]);
  }
  float xx = 0.f;
  #pragma unroll 1
  for (int o=0;o<64;o++){
    float a = 0.f;
    #pragma unroll
    for (int c=0;c<64;c++) a += wf[WF_W2+o*64+c]*h1[c];
    float h2 = lrelu(wf[WF_G2+o]*a + wf[WF_B2+o]);
    ws[OFF_H2 + (long)n*64 + o] = h2;
    xx += h2*h2;
  }
  ws[OFF_XX + n] = xx;
  ws[OFF_X + n] = x0; ws[OFF_Y + n] = x1; ws[OFF_Z + n] = x2;
  ws[OFF_XXC + n] = x0*x0 + x1*x1 + x2*x2;
}

// ---------------- K2a: pair GEMM (fp32), per batch chunk --------------------
__global__ __launch_bounds__(256) void k_pair(const float* __restrict__ ws, float* __restrict__ pair,
                                              int b, int n0){
  __shared__ float As[64*128];
  __shared__ float Bs[64*128];
  int t = threadIdx.x;
  int bx = blockIdx.x, by = blockIdx.y;
  const float* h2 = ws + OFF_H2 + (long)b*N_*64;

  int r = t >> 1, c0 = (t & 1)*32;
  const float4* arow = (const float4*)(h2 + (long)(n0 + by*128 + r)*64 + c0);
  const float4* brow = (const float4*)(h2 + (long)(bx*128 + r)*64 + c0);
  #pragma unroll
  for (int q=0;q<8;q++){
    float4 av = arow[q];
    As[(c0+4*q+0)*128 + r] = av.x; As[(c0+4*q+1)*128 + r] = av.y;
    As[(c0+4*q+2)*128 + r] = av.z; As[(c0+4*q+3)*128 + r] = av.w;
    float4 bv = brow[q];
    Bs[(c0+4*q+0)*128 + r] = bv.x; Bs[(c0+4*q+1)*128 + r] = bv.y;
    Bs[(c0+4*q+2)*128 + r] = bv.z; Bs[(c0+4*q+3)*128 + r] = bv.w;
  }
  __syncthreads();

  int tr = t/16, tc = t%16;
  float acc[8][8] = {};
  #pragma unroll 4
  for (int k=0;k<64;k++){
    const float4* ap = (const float4*)&As[k*128 + tr*8];
    const float4* bp = (const float4*)&Bs[k*128 + tc*8];
    float4 a0 = ap[0], a1 = ap[1], c0v = bp[0], c1v = bp[1];
    float a[8] = {a0.x,a0.y,a0.z,a0.w,a1.x,a1.y,a1.z,a1.w};
    float c[8] = {c0v.x,c0v.y,c0v.z,c0v.w,c1v.x,c1v.y,c1v.z,c1v.w};
    #pragma unroll
    for (int i=0;i<8;i++)
      #pragma unroll
      for (int j=0;j<8;j++) acc[i][j] += a[i]*c[j];
  }
  const float* xxp = ws + OFF_XX + b*N_ + bx*128 + tc*8;
  float xxm[8];
  #pragma unroll
  for (int j=0;j<8;j++) xxm[j] = xxp[j];
  #pragma unroll
  for (int i=0;i<8;i++){
    long row = (long)(by*128 + tr*8 + i)*N_ + bx*128 + tc*8;
    float4 o0 = make_float4(2.f*acc[i][0]-xxm[0], 2.f*acc[i][1]-xxm[1],
                            2.f*acc[i][2]-xxm[2], 2.f*acc[i][3]-xxm[3]);
    float4 o1 = make_float4(2.f*acc[i][4]-xxm[4], 2.f*acc[i][5]-xxm[5],
                            2.f*acc[i][6]-xxm[6], 2.f*acc[i][7]-xxm[7]);
    ((float4*)(pair+row))[0] = o0;
    ((float4*)(pair+row))[1] = o1;
  }
}

// ---------------- K2b: top-20 over stored pair rows -------------------------
__global__ __launch_bounds__(64) void k_topk_pair(const float* __restrict__ pair, int* __restrict__ idx1,
                                                  int b, int n0){
  __shared__ float row[4160];
  int lane = threadIdx.x;
  const float4* src = (const float4*)(pair + (long)blockIdx.x*N_);
  float mv = -3.0e38f; uint32_t mi = 0;
  #pragma unroll
  for (int q=0;q<16;q++){
    float4 v = src[lane + 64*q];
    uint32_t m0 = 4u*(uint32_t)lane + 256u*q;
    *(float4*)&row[(m0 >> 6)*65 + (m0 & 63u)] = v;
    if (v.x > mv){ mv = v.x; mi = m0; }
    if (v.y > mv){ mv = v.y; mi = m0+1; }
    if (v.z > mv){ mv = v.z; mi = m0+2; }
    if (v.w > mv){ mv = v.w; mi = m0+3; }
  }
  uint64_t K = ((uint64_t)fsort(mv) << 32) | (uint32_t)(~mi);
  __syncthreads();
  topk_iter<1>(row, K, lane, idx1 + (long)(b*N_ + n0 + blockIdx.x)*KNN);
}

// ---------------- K3: fused coord-space kNN (MODE-1 fill, float4) -----------
__global__ __launch_bounds__(64) void k_knn2(const float* __restrict__ ws, int* __restrict__ idx2){
  __shared__ float row[4160];
  int n = blockIdx.x, lane = threadIdx.x;
  int base = n & ~4095;
  const float* Xp = ws + OFF_X, *Yp = ws + OFF_Y, *Zp = ws + OFF_Z, *Cp = ws + OFF_XXC;
  float xn = Xp[n], yn = Yp[n], zn = Zp[n];
  float mv = -3.0e38f; uint32_t mi = 0;
  #pragma unroll 4
  for (int q=0;q<16;q++){
    uint32_t m0 = 4u*(uint32_t)lane + 256u*q;
    float4 X4 = *(const float4*)(Xp + base + m0);
    float4 Y4 = *(const float4*)(Yp + base + m0);
    float4 Z4 = *(const float4*)(Zp + base + m0);
    float4 C4 = *(const float4*)(Cp + base + m0);
    float4 d;
    d.x = 2.f*(xn*X4.x + yn*Y4.x + zn*Z4.x) - C4.x;
    d.y = 2.f*(xn*X4.y + yn*Y4.y + zn*Z4.y) - C4.y;
    d.z = 2.f*(xn*X4.z + yn*Y4.z + zn*Z4.z) - C4.z;
    d.w = 2.f*(xn*X4.w + yn*Y4.w + zn*Z4.w) - C4.w;
    *(float4*)&row[(m0 >> 6)*65 + (m0 & 63u)] = d;
    if (d.x > mv){ mv = d.x; mi = m0; }
    if (d.y > mv){ mv = d.y; mi = m0+1; }
    if (d.z > mv){ mv = d.z; mi = m0+2; }
    if (d.w > mv){ mv = d.w; mi = m0+3; }
  }
  uint64_t K = ((uint64_t)fsort(mv) << 32) | (uint32_t)(~mi);
  __syncthreads();
  topk_iter<1>(row, K, lane, idx2 + (long)n*KNN);
}

// ---------------- K3b: u = (Wa-Wb)h2, v = Wb h2 (post-kNN) ------------------
__global__ void k_uv(float* __restrict__ ws){
  const float* wf = ws + OFF_WF;
  int n = blockIdx.x*256 + threadIdx.x;
  float h[64];
  const float4* src = (const float4*)(ws + OFF_H2 + (long)n*64);
  #pragma unroll
  for (int q=0;q<16;q++){ float4 v = src[q]; h[4*q]=v.x; h[4*q+1]=v.y; h[4*q+2]=v.z; h[4*q+3]=v.w; }
  #pragma unroll 1
  for (int o=0;o<64;o++){
    float va=0.f, vb=0.f;
    #pragma unroll
    for (int c=0;c<64;c++){
      va += wf[WF_WDG1+o*128+c]*h[c];
      vb += wf[WF_WDG1+o*128+64+c]*h[c];
    }
    ws[OFF_U + (long)n*64 + o] = va - vb;
    ws[OFF_V + (long)n*64 + o] = vb;
  }
}

// ---------------- K4/K5: edge stage (gathered first conv folded) ------------
__global__ __launch_bounds__(256) void k_edge(float* __restrict__ ws, const int* __restrict__ idxt,
      int use_u, long uoff, long goff, int w2off,
      int g1off, int b1off, int g2off, int b2off, long outoff){
  __shared__ float y1s[64*65];
  __shared__ float w2s[64*65];
  __shared__ float us [64*65];
  __shared__ float g1s[64], b1s[64], g2s[64], b2s[64];
  const float* wf = ws + OFF_WF;
  int t = threadIdx.x;
  int p0 = blockIdx.x*64;
  int b  = p0 >> 12;

  #pragma unroll 1
  for (int i=t;i<4096;i+=256){ int o = i>>6, kk = i&63; w2s[o*65+kk] = wf[w2off + i]; }
  if (use_u){
    #pragma unroll 1
    for (int i=t;i<4096;i+=256){ int e = i>>6, c = i&63; us[e*65+c] = ws[uoff + (long)(p0+e)*64 + c]; }
  }
  if (t < 64){ g1s[t]=wf[g1off+t]; b1s[t]=wf[b1off+t]; g2s[t]=wf[g2off+t]; b2s[t]=wf[b2off+t]; }
  __syncthreads();

  int lane = t & 63, wv = t >> 6;
  int tr = t & 15, oc = t >> 4;
  float mx[4][4];
  #pragma unroll
  for (int i=0;i<4;i++)
    #pragma unroll
    for (int j=0;j<4;j++) mx[i][j] = -3.0e38f;

  for (int k=0;k<KNN;k++){
    #pragma unroll 4
    for (int jj=0;jj<16;jj++){
      int e  = wv + 4*jj;
      int nb = idxt[(long)(p0+e)*KNN + k];
      float val = ws[goff + ((long)(b<<12) + nb)*64 + lane];
      if (use_u) val += us[e*65 + lane];
      y1s[e*65 + lane] = lrelu(g1s[lane]*val + b1s[lane]);
    }
    __syncthreads();
    float acc[4][4] = {};
    #pragma unroll 4
    for (int kk=0;kk<64;kk++){
      float a0 = y1s[(tr   )*65+kk], a1 = y1s[(tr+16)*65+kk];
      float a2 = y1s[(tr+32)*65+kk], a3 = y1s[(tr+48)*65+kk];
      float c0 = w2s[(oc   )*65+kk], c1 = w2s[(oc+16)*65+kk];
      float c2 = w2s[(oc+32)*65+kk], c3 = w2s[(oc+48)*65+kk];
      acc[0][0]+=a0*c0; acc[0][1]+=a0*c1; acc[0][2]+=a0*c2; acc[0][3]+=a0*c3;
      acc[1][0]+=a1*c0; acc[1][1]+=a1*c1; acc[1][2]+=a1*c2; acc[1][3]+=a1*c3;
      acc[2][0]+=a2*c0; acc[2][1]+=a2*c1; acc[2][2]+=a2*c2; acc[2][3]+=a2*c3;
      acc[3][0]+=a3*c0; acc[3][1]+=a3*c1; acc[3][2]+=a3*c2; acc[3][3]+=a3*c3;
    }
    #pragma unroll
    for (int i=0;i<4;i++)
      #pragma unroll
      for (int j=0;j<4;j++){
        int o = oc + 16*j;
        float yy = lrelu(g2s[o]*acc[i][j] + b2s[o]);
        mx[i][j] = fmaxf(mx[i][j], yy);
      }
    __syncthreads();
  }
  #pragma unroll
  for (int i=0;i<4;i++)
    #pragma unroll
    for (int j=0;j<4;j++)
      ws[outoff + (long)(p0 + tr + 16*i)*64 + oc + 16*j] = mx[i][j];
}

// ---------------- K4b: w = Wsn1 . hdg per point (stored raw) ----------------
__global__ void k_w(float* __restrict__ ws){
  const float* wf = ws + OFF_WF;
  int n = blockIdx.x*256 + threadIdx.x;
  float h[64];
  const float4* src = (const float4*)(ws + OFF_HDG + (long)n*64);
  #pragma unroll
  for (int q=0;q<16;q++){ float4 v = src[q]; h[4*q]=v.x; h[4*q+1]=v.y; h[4*q+2]=v.z; h[4*q+3]=v.w; }
  #pragma unroll 1
  for (int o=0;o<64;o++){
    float a = 0.f;
    #pragma unroll
    for (int c=0;c<64;c++) a += wf[WF_WSN1 + o*64 + c]*h[c];
    ws[OFF_U + (long)n*64 + o] = a;
  }
}

// ---------------- K6a: head conv3+conv4, h4 out in k-major [128][NP] --------
__global__ __launch_bounds__(256) void k_h4(const float* __restrict__ ws, float* __restrict__ h4g){
  __shared__ float Hs[64*65];    // [ch][pt] (hsn), then reused as [o3][pt] (h3)
  __shared__ float wb[64*130];   // W3 as wb[c*65+o]; later W4 as wb[c*130+o]
  const float* wf = ws + OFF_WF;
  int t = threadIdx.x;
  int p0 = blockIdx.x*64;

  {
    int r = t >> 2, c0 = (t & 3)*16;
    const float4* src = (const float4*)(ws + OFF_H2 + (long)(p0 + r)*64 + c0);
    #pragma unroll
    for (int q=0;q<4;q++){
      float4 v = src[q];
      Hs[(c0+4*q+0)*65 + r] = v.x; Hs[(c0+4*q+1)*65 + r] = v.y;
      Hs[(c0+4*q+2)*65 + r] = v.z; Hs[(c0+4*q+3)*65 + r] = v.w;
    }
  }
  {
    int r = t >> 2, c0 = (t & 3)*16;
    const float4* src = (const float4*)(wf + WF_W3 + (long)r*64 + c0);
    #pragma unroll
    for (int q=0;q<4;q++){
      float4 v = src[q];
      wb[(c0+4*q+0)*65 + r] = v.x; wb[(c0+4*q+1)*65 + r] = v.y;
      wb[(c0+4*q+2)*65 + r] = v.z; wb[(c0+4*q+3)*65 + r] = v.w;
    }
  }
  __syncthreads();

  int pr = t & 15, og = t >> 4;
  float acc[4][4] = {};
  #pragma unroll 8
  for (int k=0;k<64;k++){
    float4 a = *(const float4*)&Hs[k*65 + pr*4];
    float4 c = *(const float4*)&wb[k*65 + og*4];
    float av[4] = {a.x,a.y,a.z,a.w}, cv[4] = {c.x,c.y,c.z,c.w};
    #pragma unroll
    for (int i=0;i<4;i++)
      #pragma unroll
      for (int j=0;j<4;j++) acc[i][j] += av[i]*cv[j];
  }
  __syncthreads();

  #pragma unroll
  for (int j=0;j<4;j++){
    int o = og*4 + j;
    float g3 = wf[WF_G3+o], b3 = wf[WF_B3+o];
    #pragma unroll
    for (int i=0;i<4;i++)
      Hs[o*65 + pr*4 + i] = lrelu(g3*acc[i][j] + b3);
  }
  {
    int r = t >> 1, c0 = (t & 1)*32;
    const float4* src = (const float4*)(wf + WF_W4 + (long)r*64 + c0);
    #pragma unroll
    for (int q=0;q<8;q++){
      float4 v = src[q];
      wb[(c0+4*q+0)*130 + r] = v.x; wb[(c0+4*q+1)*130 + r] = v.y;
      wb[(c0+4*q+2)*130 + r] = v.z; wb[(c0+4*q+3)*130 + r] = v.w;
    }
  }
  __syncthreads();

  float a2[4][8] = {};
  #pragma unroll 8
  for (int k=0;k<64;k++){
    float4 a = *(const float4*)&Hs[k*65 + pr*4];
    float4 c0 = *(const float4*)&wb[k*130 + og*8];
    float4 c1 = *(const float4*)&wb[k*130 + og*8 + 4];
    float av[4] = {a.x,a.y,a.z,a.w};
    float cv[8] = {c0.x,c0.y,c0.z,c0.w,c1.x,c1.y,c1.z,c1.w};
    #pragma unroll
    for (int i=0;i<4;i++)
      #pragma unroll
      for (int j=0;j<8;j++) a2[i][j] += av[i]*cv[j];
  }
  #pragma unroll
  for (int j=0;j<8;j++){
    int o = og*8 + j;
    float g4 = wf[WF_G4+o], b4 = wf[WF_B4+o];
    #pragma unroll
    for (int i=0;i<4;i++)
      h4g[(long)o*NP + p0 + pr*4 + i] = lrelu(g4*a2[i][j] + b4);
  }
}

// ---------------- K6b: conv5 GEMM [512 x 128] . [128 x NP] ------------------
#define KC 32
__global__ __launch_bounds__(256) void k_conv5(const float* __restrict__ ws, void* __restrict__ outv){
  __shared__ float As[KC*128];   // [k][o]
  __shared__ float Bs[KC*128];   // [k][pt]
  const float* wf = ws + OFF_WF;
  int f = ((const int*)(ws + OFF_FLAG))[0];
  int t = threadIdx.x;
  int p0 = blockIdx.x*128;
  int o0 = blockIdx.y*128;
  const float* H4 = ws + OFF_H4;
  float acc[8][8] = {};

  for (int kc = 0; kc < 128; kc += KC){
    {
      int r = t >> 1, c0 = (t & 1)*16;
      const float4* src = (const float4*)(wf + WF_W5 + (long)(o0 + r)*128 + kc + c0);
      #pragma unroll
      for (int q=0;q<4;q++){
        float4 v = src[q];
        As[(c0+4*q+0)*128 + r] = v.x; As[(c0+4*q+1)*128 + r] = v.y;
        As[(c0+4*q+2)*128 + r] = v.z; As[(c0+4*q+3)*128 + r] = v.w;
      }
    }
    {
      int kr = t >> 3, pc = (t & 7)*16;
      const float4* src = (const float4*)(H4 + (long)(kc + kr)*NP + p0 + pc);
      float4 v0 = src[0], v1 = src[1], v2 = src[2], v3 = src[3];
      *(float4*)&Bs[kr*128 + pc     ] = v0;
      *(float4*)&Bs[kr*128 + pc + 4 ] = v1;
      *(float4*)&Bs[kr*128 + pc + 8 ] = v2;
      *(float4*)&Bs[kr*128 + pc + 12] = v3;
    }
    __syncthreads();
    int tr = t/16, tc = t%16;
    #pragma unroll 8
    for (int k=0;k<KC;k++){
      const float4* ap = (const float4*)&As[k*128 + tr*8];
      const float4* bp = (const float4*)&Bs[k*128 + tc*8];
      float4 a0 = ap[0], a1 = ap[1], b0 = bp[0], b1 = bp[1];
      float a[8] = {a0.x,a0.y,a0.z,a0.w,a1.x,a1.y,a1.z,a1.w};
      float b[8] = {b0.x,b0.y,b0.z,b0.w,b1.x,b1.y,b1.z,b1.w};
      #pragma unroll
      for (int i=0;i<8;i++)
        #pragma unroll
        for (int j=0;j<8;j++) acc[i][j] += a[i]*b[j];
    }
    __syncthreads();
  }

  int tr = t/16, tc = t%16;
  int b = p0 >> 12, nn = (p0 & 4095) + tc*8;
  #pragma unroll
  for (int i=0;i<8;i++){
    int oo = o0 + tr*8 + i;
    float g5 = wf[WF_G5+oo], b5 = wf[WF_B5+oo];
    long base = ((long)(b*512 + oo) << 12) + nn;
    if (f){
      float4 v0 = make_float4(lrelu(g5*acc[i][0]+b5), lrelu(g5*acc[i][1]+b5),
                              lrelu(g5*acc[i][2]+b5), lrelu(g5*acc[i][3]+b5));
      float4 v1 = make_float4(lrelu(g5*acc[i][4]+b5), lrelu(g5*acc[i][5]+b5),
                              lrelu(g5*acc[i][6]+b5), lrelu(g5*acc[i][7]+b5));
      *(float4*)((float*)outv + base)     = v0;
      *(float4*)((float*)outv + base + 4) = v1;
    } else {
      #pragma unroll
      for (int j=0;j<8;j++)
        ((bf16*)outv)[base + j] = __float2bfloat16(lrelu(g5*acc[i][j] + b5));
    }
  }
}

// ---------------- host ------------------------------------------------------
extern "C" void kernel_launch(void* const* d_in, const int* in_sizes, int n_in,
                              void* d_out, int out_size, void* d_ws, size_t ws_size,
                              hipStream_t stream) {
  const void* X = d_in[0];
  float* ws = (float*)d_ws;
  int* flagp = (int*)(ws + OFF_FLAG);

  WPack pk;
  static const int wsz[27] = {192,64,64, 4096,64,64, 8192,64,64, 4096,64,64, 4096,64,64,
                              4096,64,64, 4096,64,64, 8192,128,128, 65536,512,512};
  int off = 0;
  for (int i=0;i<27;i++){ pk.p[i] = d_in[i+1]; pk.off[i] = off; off += wsz[i]; }
  pk.off[27] = off;

  k_detect<<<dim3(1), dim3(64), 0, stream>>>(X, flagp);
  k_wcvt<<<dim3((WF_END+255)/256), dim3(256), 0, stream>>>(pk, ws + OFF_WF, flagp);
  k_point<<<dim3(NP/256), dim3(256), 0, stream>>>(X, ws);
  k_knn2<<<dim3(NP), dim3(64), 0, stream>>>(ws, (int*)(ws + OFF_IDX2));

  long availf = (long)(ws_size/4) - OFF_PAIR;
  int chunk = 4096;
  if (availf < (long)N_*N_){
    long c = (availf / N_) & ~127L;
    chunk = (int)(c < 128 ? 128 : c);
    if (chunk > 4096) chunk = 4096;
  }
  for (int b=0;b<8;b++){
    for (int n0=0;n0<N_; n0+=chunk){
      int rows = (N_ - n0 < chunk) ? (N_ - n0) : chunk;
      k_pair<<<dim3(32, rows/128), dim3(256), 0, stream>>>(ws, ws + OFF_PAIR, b, n0);
      k_topk_pair<<<dim3(rows), dim3(64), 0, stream>>>(ws + OFF_PAIR, (int*)(ws + OFF_IDX1), b, n0);
    }
  }
  k_uv<<<dim3(NP/256), dim3(256), 0, stream>>>(ws);
  k_edge<<<dim3(NP/64), dim3(256), 0, stream>>>(ws, (const int*)(ws + OFF_IDX1),
        1, OFF_U, OFF_V, WF_WDG2, WF_GDG1, WF_BDG1, WF_GDG2, WF_BDG2, OFF_HDG);
  k_w<<<dim3(NP/256), dim3(256), 0, stream>>>(ws);
  k_edge<<<dim3(NP/64), dim3(256), 0, stream>>>(ws, (const int*)(ws + OFF_IDX2),
        0, 0, OFF_U, WF_WSN2, WF_GSN1, WF_BSN1, WF_GSN2, WF_BSN2, OFF_H2);
  k_h4<<<dim3(NP/64), dim3(256), 0, stream>>>(ws, ws + OFF_H4);
  k_conv5<<<dim3(NP/128, 4), dim3(256), 0, stream>>>(ws, d_out);
}